// Round 3
// baseline (4009.665 us; speedup 1.0000x reference)
//
#include <hip/hip_runtime.h>
#include <math.h>

#define NN   1024
#define TTL  128
#define NTP  131072   // NN*TTL
#define TOPK 30

// ---- weight region offsets (in floats) ----
#define OEGTF_T 0
#define OEGTF_C 48
#define OEGTF_B 96
#define OEGTG_T 112
#define OEGTG_C 160
#define OEGTG_B 208
#define OEE0    224
#define OEE1    736
#define OEE2    1248
#define OEEB    1760
#define OEOUT_W 1792
#define OEOUT_B 3840
#define ODTF_B  16192
#define ODTG_B  28544
#define ODEB    34752
#define OWC     34784
#define OBC     34816
#define ODEALL  59456   // [i][96]: [0:32]=E1, [32:64]=E2, [64:96]=E0 (6144)
#define ODTW2   65600   // folded (tconv.eout): [oc][j=32][96] f taps 0..47, g taps 48..95 (12288)
#define OCF     77888   // f per-tap consts [oc][o][k] (192)
#define OCG     78080   // g per-tap consts (192)
#define WTOT    78272

// ============ setup kernels ============
// All folding math in fp64, stored as fp32 for the pipeline.

__global__ void k_prep_weights(
    const float* __restrict__ w_start, const float* __restrict__ b_start,
    const float* __restrict__ etf_w, const float* __restrict__ etf_b,
    const float* __restrict__ etg_w, const float* __restrict__ etg_b,
    const float* __restrict__ eg1_w, const float* __restrict__ eg1_b,
    const float* __restrict__ eg2_w, const float* __restrict__ eg2_b,
    const float* __restrict__ eend_w, const float* __restrict__ eend_b,
    const float* __restrict__ eout_w, const float* __restrict__ eout_b,
    const float* __restrict__ dtf_w, const float* __restrict__ dtf_b,
    const float* __restrict__ dtg_w, const float* __restrict__ dtg_b,
    const float* __restrict__ dg1_w, const float* __restrict__ dg1_b,
    const float* __restrict__ dg2_w, const float* __restrict__ dg2_b,
    const float* __restrict__ dend_w, const float* __restrict__ dend_b,
    const float* __restrict__ dout_w, const float* __restrict__ dout_b,
    const float* __restrict__ w_end, const float* __restrict__ b_end,
    float* __restrict__ W)
{
    int tid = blockIdx.x*blockDim.x + threadIdx.x;
    int nthr = gridDim.x*blockDim.x;
    // encoder gate collapsed through w_start: tap[o][k] = sum_i w[o,i,k]*ws[i]
    for (int id=tid; id<96; id+=nthr){
        int which = id/48; int r = id%48; int o = r/3, k = r%3;
        const float* w = which ? etg_w : etf_w;
        double t=0.0, c=0.0;
        for (int i=0;i<16;i++){
            double wv = (double)w[(o*16+i)*3+k];
            t += wv*(double)w_start[i];
            c += wv*(double)b_start[i];
        }
        W[(which?OEGTG_T:OEGTF_T)+o*3+k] = (float)t;
        W[(which?OEGTG_C:OEGTF_C)+o*3+k] = (float)c;
    }
    for (int i=tid;i<16;i+=nthr){
        W[OEGTF_B+i] = etf_b[i];
        W[OEGTG_B+i] = etg_b[i];
    }
    // encoder fused (mix . end) matrices: Ee_k[i][o2] = sum_o eend_w[o2][o]*Mk[i][o]
    for (int id=tid; id<512; id+=nthr){
        int i = id>>5, o2 = id&31;
        double s0=0.0, s1=0.0, s2=0.0;
        for (int o=0;o<16;o++){
            double m0 = (double)eg1_w[o*32+i] + (double)eg2_w[o*32+i]
                      + 0.05*((double)eg1_w[o*32+16+i] + (double)eg2_w[o*32+16+i]);
            double m1 = 0.95*(double)eg1_w[o*32+16+i];
            double m2 = 0.95*(double)eg2_w[o*32+16+i];
            double ew = (double)eend_w[o2*16+o];
            s0 += ew*m0; s1 += ew*m1; s2 += ew*m2;
        }
        W[OEE0+i*32+o2]=(float)s0; W[OEE1+i*32+o2]=(float)s1; W[OEE2+i*32+o2]=(float)s2;
    }
    for (int o2=tid; o2<32; o2+=nthr){
        double s = (double)eend_b[o2];
        for (int o=0;o<16;o++) s += (double)eend_w[o2*16+o]*((double)eg1_b[o]+(double)eg2_b[o]);
        W[OEEB+o2] = (float)s;
    }
    for (int i=tid;i<64;i+=nthr){
        W[ODTF_B+i]=dtf_b[i]; W[ODTG_B+i]=dtg_b[i];
    }
    // folded decoder tconv weights: W'[oc][j][q], q<48: f (o*3+k), q>=48: g
    for (int id=tid; id<12288; id+=nthr){
        int oc = id/3072; int rem = id%3072; int j = rem/96; int q = rem%96;
        const float* w = (q<48) ? dtf_w : dtg_w;
        int q2 = (q<48) ? q : q-48;
        int o = q2/3, k = q2%3;
        double s = 0.0;
        for (int i=0;i<64;i++)
            s += (double)w[((oc*16+o)*64+i)*3+k]*(double)eout_w[i*32+j];
        W[ODTW2+id] = (float)s;
    }
    // per-tap constants from eout_b
    for (int id=tid; id<384; id+=nthr){
        int which = id/192; int r = id%192;
        int oc = r/48; int q = r%48; int o = q/3, k = q%3;
        const float* w = which ? dtg_w : dtf_w;
        double s = 0.0;
        for (int i=0;i<64;i++)
            s += (double)w[((oc*16+o)*64+i)*3+k]*(double)eout_b[i];
        W[(which?OCG:OCF) + oc*48 + o*3 + k] = (float)s;
    }
    // decoder fused (mix . end) matrices, combined layout [i][96]
    for (int id=tid; id<6144; id+=nthr){
        int i = id/96, j = id%96;
        double s = 0.0;
        if (j < 32){
            int o2 = j;
            for (int o=0;o<64;o++){
                double m1 = 0.95*(double)dg1_w[o*128+64+i];
                s += (double)dend_w[o2*64+o]*m1;
            }
        } else if (j < 64){
            int o2 = j-32;
            for (int o=0;o<64;o++){
                double m2 = 0.95*(double)dg2_w[o*128+64+i];
                s += (double)dend_w[o2*64+o]*m2;
            }
        } else {
            int o2 = j-64;
            for (int o=0;o<64;o++){
                double m0 = (double)dg1_w[o*128+i] + (double)dg2_w[o*128+i]
                          + 0.05*((double)dg1_w[o*128+64+i] + (double)dg2_w[o*128+64+i]);
                s += (double)dend_w[o2*64+o]*m0;
            }
        }
        W[ODEALL+id] = (float)s;
    }
    for (int o2=tid; o2<32; o2+=nthr){
        double s = (double)dend_b[o2];
        for (int o=0;o<64;o++) s += (double)dend_w[o2*64+o]*((double)dg1_b[o]+(double)dg2_b[o]);
        W[ODEB+o2] = (float)s;
        double wc = 0.0;
        for (int o3=0;o3<16;o3++) wc += (double)w_end[o3]*(double)dout_w[o3*32+o2];
        W[OWC+o2] = (float)wc;
    }
    if (tid==0){
        double bc = (double)b_end[0];
        for (int o3=0;o3<16;o3++) bc += (double)w_end[o3]*(double)dout_b[o3];
        W[OBC] = (float)bc;
    }
}

// adjacency build stays fp64 so top-k SELECTION is unchanged vs baseline
__global__ void k_emb(const int* __restrict__ idxp,
                      const float* __restrict__ emb1, const float* __restrict__ emb2,
                      const float* __restrict__ l1w, const float* __restrict__ l1b,
                      const float* __restrict__ l2w, const float* __restrict__ l2b,
                      double* __restrict__ n1, double* __restrict__ n2)
{
    int id = blockIdx.x*blockDim.x + threadIdx.x;   // 65536
    int i = id>>6, d = id&63;
    int ii = idxp[i];
    double a1 = (double)l1b[d], a2 = (double)l2b[d];
    for (int k=0;k<64;k++){
        a1 += (double)emb1[ii*64+k]*(double)l1w[d*64+k];
        a2 += (double)emb2[ii*64+k]*(double)l2w[d*64+k];
    }
    n1[id] = tanh(3.0*a1);
    n2[id] = tanh(3.0*a2);
}

// 256 threads/block: 4-wave dot phase + 4-wave scan with cross-wave reduce.
// Same fp64 math, same tie-break -> selection bit-identical to 64-thread version.
__global__ __launch_bounds__(256) void k_topk(
    const double* __restrict__ n1, const double* __restrict__ n2,
    int* __restrict__ topc, double* __restrict__ topv,
    double* __restrict__ rs1, double* __restrict__ colsum)
{
    __shared__ double arow[NN];
    __shared__ double sn1[64], sn2[64];
    __shared__ double rvs[4];
    __shared__ int    rjs[4];
    int i = blockIdx.x, tid = threadIdx.x;
    int lane = tid & 63, wid = tid >> 6;
    if (tid < 64){ sn1[tid] = n1[i*64+tid]; sn2[tid] = n2[i*64+tid]; }
    __syncthreads();
    for (int jb=0;jb<4;jb++){
        int j = jb*256 + tid;
        const double* p2 = n2 + (long)j*64;
        const double* p1 = n1 + (long)j*64;
        double d1v=0.0, d2v=0.0;
        for (int d=0;d<64;d++){ d1v += sn1[d]*p2[d]; d2v += sn2[d]*p1[d]; }
        double a = tanh(3.0*(d1v - d2v));
        arow[j] = a>0.0 ? a : 0.0;
    }
    __syncthreads();
    double rsum = 0.0;
    for (int r=0;r<TOPK;r++){
        double bv = -2.0; int bj = 1<<30;
        #pragma unroll
        for (int jb=0;jb<4;jb++){
            int j = jb*256+tid;
            double v = arow[j];
            if (v>bv || (v==bv && j<bj)){ bv=v; bj=j; }
        }
        for (int off=32; off>=1; off>>=1){
            double ov = __shfl_xor(bv, off, 64);
            int    oj = __shfl_xor(bj, off, 64);
            if (ov>bv || (ov==bv && oj<bj)){ bv=ov; bj=oj; }
        }
        if (lane == 0){ rvs[wid]=bv; rjs[wid]=bj; }
        __syncthreads();
        bv = rvs[0]; bj = rjs[0];
        #pragma unroll
        for (int k2=1;k2<4;k2++){
            double ov = rvs[k2]; int oj = rjs[k2];
            if (ov>bv || (ov==bv && oj<bj)){ bv=ov; bj=oj; }
        }
        if (tid == (bj & 255)) arow[bj] = -2.0;
        if (tid == 0){
            topc[i*TOPK+r] = bj;
            topv[i*TOPK+r] = bv;
            if (bv > 0.0) atomicAdd(&colsum[bj], bv);
        }
        rsum += (bv > 0.0 ? bv : 0.0);
        __syncthreads();
    }
    if (tid == 0) rs1[i] = 1.0 + rsum;
}

__global__ void k_csc(const int* __restrict__ topc, const double* __restrict__ topv,
                      const double* __restrict__ rs1,
                      int* __restrict__ ccount, int* __restrict__ cidx, float* __restrict__ cw)
{
    int w = blockIdx.x*blockDim.x + threadIdx.x;
    if (w >= NN) return;
    double rv = rs1[w];
    for (int r=0;r<TOPK;r++){
        double v = topv[w*TOPK+r];
        if (v > 0.0){
            int col = topc[w*TOPK+r];
            int pos = atomicAdd(&ccount[col], 1);
            cidx[(long)col*NN+pos] = w;
            cw  [(long)col*NN+pos] = (float)(v / rv);
        }
    }
}

// pad each column's edge list to a multiple of 8 with zero-weight edges
__global__ void k_pad(int* __restrict__ ccount, int* __restrict__ cidx, float* __restrict__ cw)
{
    int col = blockIdx.x*blockDim.x + threadIdx.x;
    if (col >= NN) return;
    int cnt = ccount[col];
    int padded = (cnt + 7) & ~7;
    for (int e = cnt; e < padded; e++){
        cidx[(long)col*NN + e] = 0;
        cw  [(long)col*NN + e] = 0.0f;
    }
    ccount[col] = padded;
}

__global__ void k_post1(const double* __restrict__ colsum, const double* __restrict__ rs1,
                        double* __restrict__ rs2, float* __restrict__ d1, float* __restrict__ d2)
{
    int v = blockIdx.x*blockDim.x + threadIdx.x;
    if (v >= NN) return;
    double r2 = 1.0 + colsum[v];
    rs2[v] = r2;
    d2[v] = (float)(1.0/r2);
    d1[v] = (float)(1.0/rs1[v]);
}

// dir-1 edge lists repacked to padded [w][32] (int4/float4-aligned)
__global__ void k_post2(const int* __restrict__ topc, const double* __restrict__ topv,
                        const double* __restrict__ rs2,
                        int* __restrict__ topc2, float* __restrict__ ew2b)
{
    int e = blockIdx.x*blockDim.x + threadIdx.x;
    if (e >= NN*32) return;
    int w = e>>5, r = e&31;
    if (r < TOPK){
        double v = topv[w*TOPK+r];
        int c = topc[w*TOPK+r];
        topc2[e] = (v > 0.0) ? c : 0;
        ew2b[e]  = (v > 0.0) ? (float)(v / rs2[c]) : 0.0f;
    } else {
        topc2[e] = 0;
        ew2b[e]  = 0.0f;
    }
}

// ============ pipeline kernels (planes [ch][t][v], fp32, v contiguous) ============

// encoder: gate (collapsed taps) computed from x[B,T,N] directly (no transpose),
// staged as float4 (4 t-values) per v in LDS, then both graph gathers.
__global__ __launch_bounds__(256) void k_enc_gg(const float* __restrict__ x,
    float* __restrict__ eg, float* __restrict__ es1, float* __restrict__ es2,
    const float* __restrict__ Wt,
    const int* __restrict__ ccount, const int* __restrict__ cidx, const float* __restrict__ cw,
    const int* __restrict__ topc2, const float* __restrict__ ew2b,
    const float* __restrict__ d1, const float* __restrict__ d2,
    long S, int b0)
{
    __shared__ float4 lds4[NN];   // 16 KB: [v] -> gate at t0..t0+3
    int tid = threadIdx.x, c = blockIdx.y, cb = blockIdx.z, t0 = blockIdx.x*4;
    float ft[3], fc[3], gt[3], gcc[3];
    #pragma unroll
    for (int k=0;k<3;k++){
        ft[k]=Wt[OEGTF_T+c*3+k]; fc[k]=Wt[OEGTF_C+c*3+k];
        gt[k]=Wt[OEGTG_T+c*3+k]; gcc[k]=Wt[OEGTG_C+c*3+k];
    }
    float fb = Wt[OEGTF_B+c], gb = Wt[OEGTG_B+c];
    const float* xb = x + (long)(b0+cb)*NTP + (long)t0*NN;
    long base = (long)c*S + (long)cb*NTP + (long)t0*NN;
    bool hl0 = (t0>0), hr3 = (t0+4<TTL);
    for (int q=0;q<4;q++){
        int v = q*256 + tid;
        float xm = hl0 ? xb[v-NN] : 0.0f;
        float x0 = xb[v], x1 = xb[v+NN], x2 = xb[v+2*NN], x3 = xb[v+3*NN];
        float xq = hr3 ? xb[v+4*NN] : 0.0f;
        float g0,g1,g2,g3;
        {
            float atf = fb + ft[1]*x0 + fc[1], atg = gb + gt[1]*x0 + gcc[1];
            if (hl0){ atf += ft[0]*xm + fc[0]; atg += gt[0]*xm + gcc[0]; }
            atf += ft[2]*x1 + fc[2]; atg += gt[2]*x1 + gcc[2];
            g0 = tanhf(atf)/(1.0f+expf(-atg));
        }
        {
            float atf = fb + ft[0]*x0 + fc[0] + ft[1]*x1 + fc[1] + ft[2]*x2 + fc[2];
            float atg = gb + gt[0]*x0 + gcc[0] + gt[1]*x1 + gcc[1] + gt[2]*x2 + gcc[2];
            g1 = tanhf(atf)/(1.0f+expf(-atg));
        }
        {
            float atf = fb + ft[0]*x1 + fc[0] + ft[1]*x2 + fc[1] + ft[2]*x3 + fc[2];
            float atg = gb + gt[0]*x1 + gcc[0] + gt[1]*x2 + gcc[1] + gt[2]*x3 + gcc[2];
            g2 = tanhf(atf)/(1.0f+expf(-atg));
        }
        {
            float atf = fb + ft[0]*x2 + fc[0] + ft[1]*x3 + fc[1];
            float atg = gb + gt[0]*x2 + gcc[0] + gt[1]*x3 + gcc[1];
            if (hr3){ atf += ft[2]*xq + fc[2]; atg += gt[2]*xq + gcc[2]; }
            g3 = tanhf(atf)/(1.0f+expf(-atg));
        }
        lds4[v] = make_float4(g0,g1,g2,g3);
        eg[base+v] = g0; eg[base+NN+v] = g1; eg[base+2*NN+v] = g2; eg[base+3*NN+v] = g3;
    }
    __syncthreads();
    for (int wb=0;wb<4;wb++){
        int w = wb*256 + tid;
        float4 gw = lds4[w];
        float dv = d1[w];
        float a0=gw.x*dv, a1=gw.y*dv, a2=gw.z*dv, a3=gw.w*dv;
        int cnt = ccount[w];               // padded to multiple of 8
        const int4*   ci4 = (const int4*)  (cidx + (long)w*NN);
        const float4* cw4 = (const float4*)(cw   + (long)w*NN);
        for (int e=0; e<cnt; e+=8){
            int4 ia = ci4[e>>2], ib = ci4[(e>>2)+1];
            float4 wa = cw4[e>>2], wc = cw4[(e>>2)+1];
            float4 s;
            s = lds4[ia.x]; a0 += wa.x*s.x; a1 += wa.x*s.y; a2 += wa.x*s.z; a3 += wa.x*s.w;
            s = lds4[ia.y]; a0 += wa.y*s.x; a1 += wa.y*s.y; a2 += wa.y*s.z; a3 += wa.y*s.w;
            s = lds4[ia.z]; a0 += wa.z*s.x; a1 += wa.z*s.y; a2 += wa.z*s.z; a3 += wa.z*s.w;
            s = lds4[ia.w]; a0 += wa.w*s.x; a1 += wa.w*s.y; a2 += wa.w*s.z; a3 += wa.w*s.w;
            s = lds4[ib.x]; a0 += wc.x*s.x; a1 += wc.x*s.y; a2 += wc.x*s.z; a3 += wc.x*s.w;
            s = lds4[ib.y]; a0 += wc.y*s.x; a1 += wc.y*s.y; a2 += wc.y*s.z; a3 += wc.y*s.w;
            s = lds4[ib.z]; a0 += wc.z*s.x; a1 += wc.z*s.y; a2 += wc.z*s.z; a3 += wc.z*s.w;
            s = lds4[ib.w]; a0 += wc.w*s.x; a1 += wc.w*s.y; a2 += wc.w*s.z; a3 += wc.w*s.w;
        }
        es1[base+w]=a0; es1[base+NN+w]=a1; es1[base+2*NN+w]=a2; es1[base+3*NN+w]=a3;
        float dw = d2[w];
        float b0a=gw.x*dw, b1a=gw.y*dw, b2a=gw.z*dw, b3a=gw.w*dw;
        const int4*   tc4 = (const int4*)  (topc2 + w*32);
        const float4* e24 = (const float4*)(ew2b  + w*32);
        #pragma unroll
        for (int r=0;r<8;r++){
            int4 ic = tc4[r]; float4 wv = e24[r];
            float4 s;
            s = lds4[ic.x]; b0a += wv.x*s.x; b1a += wv.x*s.y; b2a += wv.x*s.z; b3a += wv.x*s.w;
            s = lds4[ic.y]; b0a += wv.y*s.x; b1a += wv.y*s.y; b2a += wv.y*s.z; b3a += wv.y*s.w;
            s = lds4[ic.z]; b0a += wv.z*s.x; b1a += wv.z*s.y; b2a += wv.z*s.z; b3a += wv.z*s.w;
            s = lds4[ic.w]; b0a += wv.w*s.x; b1a += wv.w*s.y; b2a += wv.w*s.z; b3a += wv.w*s.w;
        }
        es2[base+w]=b0a; es2[base+NN+w]=b1a; es2[base+2*NN+w]=b2a; es2[base+3*NN+w]=b3a;
    }
}

// encoder tail: fused (mix.end) -> relu -> e32 planes (pointwise, layout-agnostic)
__global__ __launch_bounds__(256) void k_enc_tail(const float* __restrict__ Bp,
    float* __restrict__ E32, const float* __restrict__ Wt, long S)
{
    long p = (long)blockIdx.x*256 + threadIdx.x;
    float e[32];
    #pragma unroll
    for (int o2=0;o2<32;o2++) e[o2] = Wt[OEEB+o2];
    for (int i=0;i<16;i++){
        float a = Bp[(long)i*S+p], b = Bp[(long)(16+i)*S+p], c = Bp[(long)(32+i)*S+p];
        const float* w0 = Wt+OEE0+i*32;
        const float* w1 = Wt+OEE1+i*32;
        const float* w2 = Wt+OEE2+i*32;
        #pragma unroll
        for (int o2=0;o2<32;o2++) e[o2] += w0[o2]*a + w1[o2]*b + w2[o2]*c;
    }
    #pragma unroll
    for (int o2=0;o2<32;o2++){
        float v = e[o2];
        E32[(long)o2*S+p] = v>0.0f ? v : 0.0f;
    }
}

// decoder gated tconv, 2 t-points per thread (4 loads feed 192 FMAs per j)
__global__ __launch_bounds__(256) void k_dec_gate(const float* __restrict__ E32,
    float* __restrict__ g, const float* __restrict__ Wt, long S)
{
    int oc = blockIdx.y, cb = blockIdx.z;
    int bx = blockIdx.x;                 // vseg(0..3) + 4*tpair(0..63)
    int vseg = bx & 3, tpair = bx >> 2;
    int t0 = tpair*2;
    long pos0 = (long)cb*NTP + (long)t0*NN + vseg*256 + threadIdx.x;
    bool hasL = (t0 > 0), hasR = (t0 + 2 < TTL);
    float af0[16], ag0[16], af1[16], ag1[16];
    const float* CFo = Wt + OCF + oc*48;
    const float* CGo = Wt + OCG + oc*48;
    #pragma unroll
    for (int o=0;o<16;o++){
        float fB = Wt[ODTF_B+oc*16+o], gB = Wt[ODTG_B+oc*16+o];
        float f0 = CFo[o*3], f1 = CFo[o*3+1], f2 = CFo[o*3+2];
        float h0 = CGo[o*3], h1 = CGo[o*3+1], h2 = CGo[o*3+2];
        af0[o] = fB + f1 + f2 + (hasL ? f0 : 0.0f);
        ag0[o] = gB + h1 + h2 + (hasL ? h0 : 0.0f);
        af1[o] = fB + f0 + f1 + (hasR ? f2 : 0.0f);
        ag1[o] = gB + h0 + h1 + (hasR ? h2 : 0.0f);
    }
    #pragma unroll 2
    for (int j=0;j<32;j++){
        const float* xp = E32 + (long)j*S + pos0;
        float xl0 = hasL ? xp[-NN] : 0.0f;
        float xc0 = xp[0];
        float xc1 = xp[NN];
        float xr1 = hasR ? xp[2*NN] : 0.0f;
        const float* wfg = Wt + ODTW2 + (long)(oc*32+j)*96;
        #pragma unroll
        for (int o=0;o<16;o++){
            float w0=wfg[o*3], w1=wfg[o*3+1], w2=wfg[o*3+2];
            af0[o] += w0*xl0 + w1*xc0 + w2*xc1;
            af1[o] += w0*xc0 + w1*xc1 + w2*xr1;
            float v0=wfg[48+o*3], v1=wfg[48+o*3+1], v2=wfg[48+o*3+2];
            ag0[o] += v0*xl0 + v1*xc0 + v2*xc1;
            ag1[o] += v0*xc0 + v1*xc1 + v2*xr1;
        }
    }
    #pragma unroll
    for (int o=0;o<16;o++){
        long op = (long)(oc*16+o)*S + pos0;
        g[op]    = tanhf(af0[o])/(1.0f+expf(-ag0[o]));
        g[op+NN] = tanhf(af1[o])/(1.0f+expf(-ag1[o]));
    }
}

// decoder fused-mix pointwise conv, SINGLE pass: one g read feeds all 96 outputs
__global__ __launch_bounds__(256) void k_dec_conv(const float* __restrict__ g,
    float* __restrict__ P12, float* __restrict__ P0p,
    const float* __restrict__ Wt, long S)
{
    long p = (long)blockIdx.x*256 + threadIdx.x;
    float a0[32], a1[32], a2[32];
    #pragma unroll
    for (int jj=0;jj<32;jj++){ a1[jj]=0.0f; a2[jj]=0.0f; a0[jj]=Wt[ODEB+jj]; }
    #pragma unroll 1
    for (int i=0;i<64;i++){
        float gv = g[(long)i*S+p];
        const float* wr = Wt + ODEALL + i*96;
        #pragma unroll
        for (int jj=0;jj<32;jj++){
            a1[jj] += wr[jj]*gv;
            a2[jj] += wr[32+jj]*gv;
            a0[jj] += wr[64+jj]*gv;
        }
    }
    #pragma unroll
    for (int jj=0;jj<32;jj++){
        P12[(long)jj*S+p]      = a1[jj];
        P12[(long)(32+jj)*S+p] = a2[jj];
        P0p[(long)jj*S+p]      = a0[jj];
    }
}

// decoder graph gather + fused tail: ch-groups of 4, each block completes Q12
// for its channels, applies relu(P0+Q12)*wc, accumulates a group-partial plane.
__global__ __launch_bounds__(256) void k_graph32f(const float* __restrict__ P1,
    const float* __restrict__ P2, const float* __restrict__ P0,
    float* __restrict__ part,
    const int* __restrict__ ccount, const int* __restrict__ cidx, const float* __restrict__ cw,
    const int* __restrict__ topc2, const float* __restrict__ ew2b,
    const float* __restrict__ d1, const float* __restrict__ d2,
    const float* __restrict__ Wt, long S)
{
    __shared__ float4 lds4[NN];   // 16 KB, re-staged per channel/dir
    int tid = threadIdx.x;
    int grp = blockIdx.y, cb = blockIdx.z, t0 = blockIdx.x*4;
    long tbase = (long)cb*NTP + (long)t0*NN;
    float res[4][4];
    #pragma unroll
    for (int wb=0;wb<4;wb++){
        #pragma unroll
        for (int k=0;k<4;k++) res[wb][k]=0.0f;
    }
    float q1[4][4];
    for (int c4=0;c4<4;c4++){
        int ch = grp*4 + c4;
        long base = (long)ch*S + tbase;
        if (c4) __syncthreads();               // protect lds4 from prev readers
        const float* s1 = P1 + base;
        for (int q=0;q<4;q++){
            int v = q*256 + tid;
            lds4[v] = make_float4(s1[v], s1[v+NN], s1[v+2*NN], s1[v+3*NN]);
        }
        __syncthreads();
        for (int wb=0;wb<4;wb++){
            int w = wb*256 + tid;
            float4 gv = lds4[w];
            float dv = d1[w];
            float a0=gv.x*dv, a1=gv.y*dv, a2=gv.z*dv, a3=gv.w*dv;
            int cnt = ccount[w];
            const int4*   ci4 = (const int4*)  (cidx + (long)w*NN);
            const float4* cw4 = (const float4*)(cw   + (long)w*NN);
            for (int e=0; e<cnt; e+=8){
                int4 ia = ci4[e>>2], ib = ci4[(e>>2)+1];
                float4 wa = cw4[e>>2], wc2 = cw4[(e>>2)+1];
                float4 s;
                s = lds4[ia.x]; a0 += wa.x*s.x; a1 += wa.x*s.y; a2 += wa.x*s.z; a3 += wa.x*s.w;
                s = lds4[ia.y]; a0 += wa.y*s.x; a1 += wa.y*s.y; a2 += wa.y*s.z; a3 += wa.y*s.w;
                s = lds4[ia.z]; a0 += wa.z*s.x; a1 += wa.z*s.y; a2 += wa.z*s.z; a3 += wa.z*s.w;
                s = lds4[ia.w]; a0 += wa.w*s.x; a1 += wa.w*s.y; a2 += wa.w*s.z; a3 += wa.w*s.w;
                s = lds4[ib.x]; a0 += wc2.x*s.x; a1 += wc2.x*s.y; a2 += wc2.x*s.z; a3 += wc2.x*s.w;
                s = lds4[ib.y]; a0 += wc2.y*s.x; a1 += wc2.y*s.y; a2 += wc2.y*s.z; a3 += wc2.y*s.w;
                s = lds4[ib.z]; a0 += wc2.z*s.x; a1 += wc2.z*s.y; a2 += wc2.z*s.z; a3 += wc2.z*s.w;
                s = lds4[ib.w]; a0 += wc2.w*s.x; a1 += wc2.w*s.y; a2 += wc2.w*s.z; a3 += wc2.w*s.w;
            }
            q1[wb][0]=a0; q1[wb][1]=a1; q1[wb][2]=a2; q1[wb][3]=a3;
        }
        __syncthreads();
        const float* s2 = P2 + base;
        for (int q=0;q<4;q++){
            int v = q*256 + tid;
            lds4[v] = make_float4(s2[v], s2[v+NN], s2[v+2*NN], s2[v+3*NN]);
        }
        __syncthreads();
        float wc = Wt[OWC+ch];
        const float* p0 = P0 + base;
        for (int wb=0;wb<4;wb++){
            int w = wb*256 + tid;
            float4 gv = lds4[w];
            float dw = d2[w];
            float c0=gv.x*dw, c1=gv.y*dw, c2=gv.z*dw, c3=gv.w*dw;
            const int4*   tc4 = (const int4*)  (topc2 + w*32);
            const float4* e24 = (const float4*)(ew2b  + w*32);
            #pragma unroll
            for (int r=0;r<8;r++){
                int4 ic = tc4[r]; float4 wv = e24[r];
                float4 s;
                s = lds4[ic.x]; c0 += wv.x*s.x; c1 += wv.x*s.y; c2 += wv.x*s.z; c3 += wv.x*s.w;
                s = lds4[ic.y]; c0 += wv.y*s.x; c1 += wv.y*s.y; c2 += wv.y*s.z; c3 += wv.y*s.w;
                s = lds4[ic.z]; c0 += wv.z*s.x; c1 += wv.z*s.y; c2 += wv.z*s.z; c3 += wv.z*s.w;
                s = lds4[ic.w]; c0 += wv.w*s.x; c1 += wv.w*s.y; c2 += wv.w*s.z; c3 += wv.w*s.w;
            }
            float e0 = p0[w]        + q1[wb][0] + c0;
            float e1 = p0[NN+w]     + q1[wb][1] + c1;
            float e2 = p0[2*NN+w]   + q1[wb][2] + c2;
            float e3 = p0[3*NN+w]   + q1[wb][3] + c3;
            e0 = e0>0.0f?e0:0.0f; e1 = e1>0.0f?e1:0.0f;
            e2 = e2>0.0f?e2:0.0f; e3 = e3>0.0f?e3:0.0f;
            res[wb][0] += wc*e0; res[wb][1] += wc*e1;
            res[wb][2] += wc*e2; res[wb][3] += wc*e3;
        }
    }
    long pb = (long)grp*S + tbase;
    for (int wb=0;wb<4;wb++){
        int w = wb*256 + tid;
        part[pb+w]      = res[wb][0];
        part[pb+NN+w]   = res[wb][1];
        part[pb+2*NN+w] = res[wb][2];
        part[pb+3*NN+w] = res[wb][3];
    }
}

// combine 8 group-partials + OBC -> out (fully contiguous store)
__global__ __launch_bounds__(256) void k_comb(const float* __restrict__ part,
    const float* __restrict__ Wt, float* __restrict__ out, long S, int b0)
{
    long p = (long)blockIdx.x*256 + threadIdx.x;
    float r = Wt[OBC];
    #pragma unroll
    for (int gp=0; gp<8; gp++) r += part[(long)gp*S+p];
    out[(long)b0*NTP + p] = r;
}

// ============ launch ============

extern "C" void kernel_launch(void* const* d_in, const int* in_sizes, int n_in,
                              void* d_out, int out_size, void* d_ws, size_t ws_size,
                              hipStream_t stream)
{
    const float* x      = (const float*)d_in[0];
    const int*   idx    = (const int*)  d_in[1];
    const float* emb1   = (const float*)d_in[2];
    const float* emb2   = (const float*)d_in[3];
    const float* lin1_w = (const float*)d_in[4];
    const float* lin1_b = (const float*)d_in[5];
    const float* lin2_w = (const float*)d_in[6];
    const float* lin2_b = (const float*)d_in[7];
    const float* w_start= (const float*)d_in[8];
    const float* b_start= (const float*)d_in[9];
    const float* etf_w  = (const float*)d_in[10];
    const float* etf_b  = (const float*)d_in[11];
    const float* etg_w  = (const float*)d_in[12];
    const float* etg_b  = (const float*)d_in[13];
    const float* eg1_w  = (const float*)d_in[14];
    const float* eg1_b  = (const float*)d_in[15];
    const float* eg2_w  = (const float*)d_in[16];
    const float* eg2_b  = (const float*)d_in[17];
    const float* eend_w = (const float*)d_in[18];
    const float* eend_b = (const float*)d_in[19];
    const float* eout_w = (const float*)d_in[20];
    const float* eout_b = (const float*)d_in[21];
    const float* dtf_w  = (const float*)d_in[22];
    const float* dtf_b  = (const float*)d_in[23];
    const float* dtg_w  = (const float*)d_in[24];
    const float* dtg_b  = (const float*)d_in[25];
    const float* dg1_w  = (const float*)d_in[26];
    const float* dg1_b  = (const float*)d_in[27];
    const float* dg2_w  = (const float*)d_in[28];
    const float* dg2_b  = (const float*)d_in[29];
    const float* dend_w = (const float*)d_in[30];
    const float* dend_b = (const float*)d_in[31];
    const float* dout_w = (const float*)d_in[32];
    const float* dout_b = (const float*)d_in[33];
    const float* w_end  = (const float*)d_in[34];
    const float* b_end  = (const float*)d_in[35];
    float* out = (float*)d_out;

    char* basep = (char*)d_ws;
    size_t cur = 0;
    auto alloc = [&](size_t bytes)->void* {
        void* p = basep + cur;
        cur = (cur + bytes + 511) & ~(size_t)511;
        return p;
    };
    float*  W     = (float*) alloc(WTOT*sizeof(float));
    double* n1    = (double*)alloc(65536*sizeof(double));
    double* n2    = (double*)alloc(65536*sizeof(double));
    double* topv  = (double*)alloc((size_t)NN*TOPK*sizeof(double));
    int*    topc  = (int*)   alloc((size_t)NN*TOPK*sizeof(int));
    double* rs1   = (double*)alloc(NN*sizeof(double));
    double* rs2   = (double*)alloc(NN*sizeof(double));
    double* colsum= (double*)alloc(NN*sizeof(double));
    float*  d1a   = (float*) alloc(NN*sizeof(float));
    float*  d2a   = (float*) alloc(NN*sizeof(float));
    int*    topc2 = (int*)   alloc((size_t)NN*32*sizeof(int));
    float*  ew2b  = (float*) alloc((size_t)NN*32*sizeof(float));
    int*    ccount= (int*)   alloc(NN*sizeof(int));
    int*    cidx  = (int*)   alloc((size_t)NN*NN*sizeof(int));
    float*  cw    = (float*) alloc((size_t)NN*NN*sizeof(float));

    // plane arena: A(64) + B(48) + C(64) channel planes of CB*NTP floats
    size_t perb = (size_t)176 * NTP * sizeof(float);
    int CB = 1;
    for (int c = 16; c >= 1; c >>= 1){
        if (cur + perb*(size_t)c <= ws_size){ CB = c; break; }
    }
    long S = (long)CB * NTP;
    float* A = (float*)alloc((size_t)64*S*sizeof(float));
    float* B = (float*)alloc((size_t)48*S*sizeof(float));
    float* C = (float*)alloc((size_t)64*S*sizeof(float));

    (void)hipMemsetAsync(colsum, 0, NN*sizeof(double), stream);
    (void)hipMemsetAsync(ccount, 0, NN*sizeof(int), stream);

    k_prep_weights<<<32,256,0,stream>>>(
        w_start,b_start, etf_w,etf_b, etg_w,etg_b, eg1_w,eg1_b, eg2_w,eg2_b,
        eend_w,eend_b, eout_w,eout_b, dtf_w,dtf_b, dtg_w,dtg_b, dg1_w,dg1_b,
        dg2_w,dg2_b, dend_w,dend_b, dout_w,dout_b, w_end,b_end, W);
    k_emb<<<256,256,0,stream>>>(idx, emb1, emb2, lin1_w, lin1_b, lin2_w, lin2_b, n1, n2);
    k_topk<<<NN,256,0,stream>>>(n1, n2, topc, topv, rs1, colsum);
    k_csc<<<4,256,0,stream>>>(topc, topv, rs1, ccount, cidx, cw);
    k_pad<<<4,256,0,stream>>>(ccount, cidx, cw);
    k_post1<<<4,256,0,stream>>>(colsum, rs1, rs2, d1a, d2a);
    k_post2<<<(NN*32+255)/256,256,0,stream>>>(topc, topv, rs2, topc2, ew2b);

    int nch = 16 / CB;
    for (int ch=0; ch<nch; ch++){
        int b0 = ch*CB;
        // encoder: fused gate+graph -> eg(B[0:16]), es1(B[16:32]), es2(B[32:48])
        k_enc_gg<<<dim3(32,16,CB),256,0,stream>>>(x, B, B+(long)16*S, B+(long)32*S, W,
            ccount,cidx,cw, topc2,ew2b, d1a,d2a, S, b0);
        // encoder tail: B[0:48] -> e32 (A[0:32])
        k_enc_tail<<<512*CB,256,0,stream>>>(B, A, W, S);
        // decoder gate (eout folded): e32(A) -> g (C[0:64])
        k_dec_gate<<<dim3(256,4,CB),256,0,stream>>>(A, C, W, S);
        // decoder fused-mix conv (single pass): g(C) -> P1,P2 (A[0:64]), P0 (B[0:32])
        k_dec_conv<<<512*CB,256,0,stream>>>(C, A, B, W, S);
        // decoder graph gather + fused tail: A(P1,P2), B(P0) -> partials (C[0:8])
        k_graph32f<<<dim3(32,8,CB),256,0,stream>>>(A, A+(long)32*S, B, C,
            ccount,cidx,cw, topc2,ew2b, d1a,d2a, W, S);
        // combine partials -> out
        k_comb<<<512*CB,256,0,stream>>>(C, W, out, S, b0);
    }
    (void)in_sizes; (void)n_in; (void)out_size;
}

// Round 4
// 3951.762 us; speedup vs baseline: 1.0147x; 1.0147x over previous
//
#include <hip/hip_runtime.h>
#include <math.h>

#define NN   1024
#define TTL  128
#define NTP  131072   // NN*TTL
#define TOPK 30

// ---- weight region offsets (in floats) ----
#define OEGTF_T 0
#define OEGTF_C 48
#define OEGTF_B 96
#define OEGTG_T 112
#define OEGTG_C 160
#define OEGTG_B 208
#define OEE0    224
#define OEE1    736
#define OEE2    1248
#define OEEB    1760
#define OEOUT_W 1792
#define OEOUT_B 3840
#define ODTF_B  16192
#define ODTG_B  28544
#define ODEB    34752
#define OWC     34784
#define OBC     34816
#define ODEALL  59456   // [i][96]: [0:32]=E1, [32:64]=E2, [64:96]=E0 (6144)
#define ODTW2   65600   // folded (tconv.eout): [oc][j=32][96] f taps 0..47, g taps 48..95 (12288)
#define OCF     77888   // f per-tap consts [oc][o][k] (192)
#define OCG     78080   // g per-tap consts (192)
#define WTOT    78272

// ============ setup kernels ============
// All folding math in fp64, stored as fp32 for the pipeline.

__global__ void k_prep_weights(
    const float* __restrict__ w_start, const float* __restrict__ b_start,
    const float* __restrict__ etf_w, const float* __restrict__ etf_b,
    const float* __restrict__ etg_w, const float* __restrict__ etg_b,
    const float* __restrict__ eg1_w, const float* __restrict__ eg1_b,
    const float* __restrict__ eg2_w, const float* __restrict__ eg2_b,
    const float* __restrict__ eend_w, const float* __restrict__ eend_b,
    const float* __restrict__ eout_w, const float* __restrict__ eout_b,
    const float* __restrict__ dtf_w, const float* __restrict__ dtf_b,
    const float* __restrict__ dtg_w, const float* __restrict__ dtg_b,
    const float* __restrict__ dg1_w, const float* __restrict__ dg1_b,
    const float* __restrict__ dg2_w, const float* __restrict__ dg2_b,
    const float* __restrict__ dend_w, const float* __restrict__ dend_b,
    const float* __restrict__ dout_w, const float* __restrict__ dout_b,
    const float* __restrict__ w_end, const float* __restrict__ b_end,
    float* __restrict__ W)
{
    int tid = blockIdx.x*blockDim.x + threadIdx.x;
    int nthr = gridDim.x*blockDim.x;
    // encoder gate collapsed through w_start: tap[o][k] = sum_i w[o,i,k]*ws[i]
    for (int id=tid; id<96; id+=nthr){
        int which = id/48; int r = id%48; int o = r/3, k = r%3;
        const float* w = which ? etg_w : etf_w;
        double t=0.0, c=0.0;
        for (int i=0;i<16;i++){
            double wv = (double)w[(o*16+i)*3+k];
            t += wv*(double)w_start[i];
            c += wv*(double)b_start[i];
        }
        W[(which?OEGTG_T:OEGTF_T)+o*3+k] = (float)t;
        W[(which?OEGTG_C:OEGTF_C)+o*3+k] = (float)c;
    }
    for (int i=tid;i<16;i+=nthr){
        W[OEGTF_B+i] = etf_b[i];
        W[OEGTG_B+i] = etg_b[i];
    }
    // encoder fused (mix . end) matrices: Ee_k[i][o2] = sum_o eend_w[o2][o]*Mk[i][o]
    for (int id=tid; id<512; id+=nthr){
        int i = id>>5, o2 = id&31;
        double s0=0.0, s1=0.0, s2=0.0;
        for (int o=0;o<16;o++){
            double m0 = (double)eg1_w[o*32+i] + (double)eg2_w[o*32+i]
                      + 0.05*((double)eg1_w[o*32+16+i] + (double)eg2_w[o*32+16+i]);
            double m1 = 0.95*(double)eg1_w[o*32+16+i];
            double m2 = 0.95*(double)eg2_w[o*32+16+i];
            double ew = (double)eend_w[o2*16+o];
            s0 += ew*m0; s1 += ew*m1; s2 += ew*m2;
        }
        W[OEE0+i*32+o2]=(float)s0; W[OEE1+i*32+o2]=(float)s1; W[OEE2+i*32+o2]=(float)s2;
    }
    for (int o2=tid; o2<32; o2+=nthr){
        double s = (double)eend_b[o2];
        for (int o=0;o<16;o++) s += (double)eend_w[o2*16+o]*((double)eg1_b[o]+(double)eg2_b[o]);
        W[OEEB+o2] = (float)s;
    }
    for (int i=tid;i<64;i+=nthr){
        W[ODTF_B+i]=dtf_b[i]; W[ODTG_B+i]=dtg_b[i];
    }
    // folded decoder tconv weights: W'[oc][j][q], q<48: f (o*3+k), q>=48: g
    for (int id=tid; id<12288; id+=nthr){
        int oc = id/3072; int rem = id%3072; int j = rem/96; int q = rem%96;
        const float* w = (q<48) ? dtf_w : dtg_w;
        int q2 = (q<48) ? q : q-48;
        int o = q2/3, k = q2%3;
        double s = 0.0;
        for (int i=0;i<64;i++)
            s += (double)w[((oc*16+o)*64+i)*3+k]*(double)eout_w[i*32+j];
        W[ODTW2+id] = (float)s;
    }
    // per-tap constants from eout_b
    for (int id=tid; id<384; id+=nthr){
        int which = id/192; int r = id%192;
        int oc = r/48; int q = r%48; int o = q/3, k = q%3;
        const float* w = which ? dtg_w : dtf_w;
        double s = 0.0;
        for (int i=0;i<64;i++)
            s += (double)w[((oc*16+o)*64+i)*3+k]*(double)eout_b[i];
        W[(which?OCG:OCF) + oc*48 + o*3 + k] = (float)s;
    }
    // decoder fused (mix . end) matrices, combined layout [i][96]
    for (int id=tid; id<6144; id+=nthr){
        int i = id/96, j = id%96;
        double s = 0.0;
        if (j < 32){
            int o2 = j;
            for (int o=0;o<64;o++){
                double m1 = 0.95*(double)dg1_w[o*128+64+i];
                s += (double)dend_w[o2*64+o]*m1;
            }
        } else if (j < 64){
            int o2 = j-32;
            for (int o=0;o<64;o++){
                double m2 = 0.95*(double)dg2_w[o*128+64+i];
                s += (double)dend_w[o2*64+o]*m2;
            }
        } else {
            int o2 = j-64;
            for (int o=0;o<64;o++){
                double m0 = (double)dg1_w[o*128+i] + (double)dg2_w[o*128+i]
                          + 0.05*((double)dg1_w[o*128+64+i] + (double)dg2_w[o*128+64+i]);
                s += (double)dend_w[o2*64+o]*m0;
            }
        }
        W[ODEALL+id] = (float)s;
    }
    for (int o2=tid; o2<32; o2+=nthr){
        double s = (double)dend_b[o2];
        for (int o=0;o<64;o++) s += (double)dend_w[o2*64+o]*((double)dg1_b[o]+(double)dg2_b[o]);
        W[ODEB+o2] = (float)s;
        double wc = 0.0;
        for (int o3=0;o3<16;o3++) wc += (double)w_end[o3]*(double)dout_w[o3*32+o2];
        W[OWC+o2] = (float)wc;
    }
    if (tid==0){
        double bc = (double)b_end[0];
        for (int o3=0;o3<16;o3++) bc += (double)w_end[o3]*(double)dout_b[o3];
        W[OBC] = (float)bc;
    }
}

// adjacency build stays fp64 so top-k SELECTION is unchanged vs baseline
__global__ void k_emb(const int* __restrict__ idxp,
                      const float* __restrict__ emb1, const float* __restrict__ emb2,
                      const float* __restrict__ l1w, const float* __restrict__ l1b,
                      const float* __restrict__ l2w, const float* __restrict__ l2b,
                      double* __restrict__ n1, double* __restrict__ n2)
{
    int id = blockIdx.x*blockDim.x + threadIdx.x;   // 65536
    int i = id>>6, d = id&63;
    int ii = idxp[i];
    double a1 = (double)l1b[d], a2 = (double)l2b[d];
    for (int k=0;k<64;k++){
        a1 += (double)emb1[ii*64+k]*(double)l1w[d*64+k];
        a2 += (double)emb2[ii*64+k]*(double)l2w[d*64+k];
    }
    n1[id] = tanh(3.0*a1);
    n2[id] = tanh(3.0*a2);
}

// single wave per row; per-lane cached local argmax: only the winning lane
// rescans its 16 slots after extraction. Same predicate/order -> selection
// bit-identical to the full-rescan version. No syncthreads in round loop.
__global__ __launch_bounds__(64) void k_topk(
    const double* __restrict__ n1, const double* __restrict__ n2,
    int* __restrict__ topc, double* __restrict__ topv,
    double* __restrict__ rs1, double* __restrict__ colsum)
{
    __shared__ double arow[NN];
    __shared__ double sn1[64], sn2[64];
    int i = blockIdx.x, lane = threadIdx.x;
    sn1[lane] = n1[i*64+lane];
    sn2[lane] = n2[i*64+lane];
    __syncthreads();
    for (int jb=0;jb<16;jb++){
        int j = jb*64 + lane;
        const double* p2 = n2 + (long)j*64;
        const double* p1 = n1 + (long)j*64;
        double d1v=0.0, d2v=0.0;
        for (int d=0;d<64;d++){ d1v += sn1[d]*p2[d]; d2v += sn2[d]*p1[d]; }
        double a = tanh(3.0*(d1v - d2v));
        arow[j] = a>0.0 ? a : 0.0;
    }
    __syncthreads();
    // per-lane cached local argmax over slots j = jb*64+lane
    double lv = -2.0; int lj = 1<<30;
    for (int jb=0;jb<16;jb++){
        int j = jb*64+lane;
        double v = arow[j];
        if (v>lv || (v==lv && j<lj)){ lv=v; lj=j; }
    }
    double rsum = 0.0;
    for (int r=0;r<TOPK;r++){
        double bv = lv; int bj = lj;
        for (int off=32; off>=1; off>>=1){
            double ov = __shfl_xor(bv, off, 64);
            int    oj = __shfl_xor(bj, off, 64);
            if (ov>bv || (ov==bv && oj<bj)){ bv=ov; bj=oj; }
        }
        if (lane == (bj & 63)){
            arow[bj] = -2.0;
            lv = -2.0; lj = 1<<30;
            for (int jb=0;jb<16;jb++){
                int j = jb*64+lane;
                double v = arow[j];
                if (v>lv || (v==lv && j<lj)){ lv=v; lj=j; }
            }
        }
        if (lane == 0){
            topc[i*TOPK+r] = bj;
            topv[i*TOPK+r] = bv;
            if (bv > 0.0) atomicAdd(&colsum[bj], bv);
        }
        rsum += (bv > 0.0 ? bv : 0.0);
    }
    if (lane == 0) rs1[i] = 1.0 + rsum;
}

__global__ void k_csc(const int* __restrict__ topc, const double* __restrict__ topv,
                      const double* __restrict__ rs1,
                      int* __restrict__ ccount, int* __restrict__ cidx, float* __restrict__ cw)
{
    int w = blockIdx.x*blockDim.x + threadIdx.x;
    if (w >= NN) return;
    double rv = rs1[w];
    for (int r=0;r<TOPK;r++){
        double v = topv[w*TOPK+r];
        if (v > 0.0){
            int col = topc[w*TOPK+r];
            int pos = atomicAdd(&ccount[col], 1);
            cidx[(long)col*NN+pos] = w;
            cw  [(long)col*NN+pos] = (float)(v / rv);
        }
    }
}

// pad each column's edge list to a multiple of 8 with zero-weight edges
__global__ void k_pad(int* __restrict__ ccount, int* __restrict__ cidx, float* __restrict__ cw)
{
    int col = blockIdx.x*blockDim.x + threadIdx.x;
    if (col >= NN) return;
    int cnt = ccount[col];
    int padded = (cnt + 7) & ~7;
    for (int e = cnt; e < padded; e++){
        cidx[(long)col*NN + e] = 0;
        cw  [(long)col*NN + e] = 0.0f;
    }
    ccount[col] = padded;
}

__global__ void k_post1(const double* __restrict__ colsum, const double* __restrict__ rs1,
                        double* __restrict__ rs2, float* __restrict__ d1, float* __restrict__ d2)
{
    int v = blockIdx.x*blockDim.x + threadIdx.x;
    if (v >= NN) return;
    double r2 = 1.0 + colsum[v];
    rs2[v] = r2;
    d2[v] = (float)(1.0/r2);
    d1[v] = (float)(1.0/rs1[v]);
}

// dir-1 edge lists repacked to padded [w][32] (int4/float4-aligned)
__global__ void k_post2(const int* __restrict__ topc, const double* __restrict__ topv,
                        const double* __restrict__ rs2,
                        int* __restrict__ topc2, float* __restrict__ ew2b)
{
    int e = blockIdx.x*blockDim.x + threadIdx.x;
    if (e >= NN*32) return;
    int w = e>>5, r = e&31;
    if (r < TOPK){
        double v = topv[w*TOPK+r];
        int c = topc[w*TOPK+r];
        topc2[e] = (v > 0.0) ? c : 0;
        ew2b[e]  = (v > 0.0) ? (float)(v / rs2[c]) : 0.0f;
    } else {
        topc2[e] = 0;
        ew2b[e]  = 0.0f;
    }
}

// ============ pipeline kernels (planes [ch][t][v], fp32, v contiguous) ============

// encoder: gate (collapsed taps) computed from x[B,T,N] directly (no transpose),
// staged as float4 (4 t-values) per v in LDS, then both graph gathers.
__global__ __launch_bounds__(256) void k_enc_gg(const float* __restrict__ x,
    float* __restrict__ eg, float* __restrict__ es1, float* __restrict__ es2,
    const float* __restrict__ Wt,
    const int* __restrict__ ccount, const int* __restrict__ cidx, const float* __restrict__ cw,
    const int* __restrict__ topc2, const float* __restrict__ ew2b,
    const float* __restrict__ d1, const float* __restrict__ d2,
    long S, int b0)
{
    __shared__ float4 lds4[NN];   // 16 KB: [v] -> gate at t0..t0+3
    int tid = threadIdx.x, c = blockIdx.y, cb = blockIdx.z, t0 = blockIdx.x*4;
    float ft[3], fc[3], gt[3], gcc[3];
    #pragma unroll
    for (int k=0;k<3;k++){
        ft[k]=Wt[OEGTF_T+c*3+k]; fc[k]=Wt[OEGTF_C+c*3+k];
        gt[k]=Wt[OEGTG_T+c*3+k]; gcc[k]=Wt[OEGTG_C+c*3+k];
    }
    float fb = Wt[OEGTF_B+c], gb = Wt[OEGTG_B+c];
    const float* xb = x + (long)(b0+cb)*NTP + (long)t0*NN;
    long base = (long)c*S + (long)cb*NTP + (long)t0*NN;
    bool hl0 = (t0>0), hr3 = (t0+4<TTL);
    for (int q=0;q<4;q++){
        int v = q*256 + tid;
        float xm = hl0 ? xb[v-NN] : 0.0f;
        float x0 = xb[v], x1 = xb[v+NN], x2 = xb[v+2*NN], x3 = xb[v+3*NN];
        float xq = hr3 ? xb[v+4*NN] : 0.0f;
        float g0,g1,g2,g3;
        {
            float atf = fb + ft[1]*x0 + fc[1], atg = gb + gt[1]*x0 + gcc[1];
            if (hl0){ atf += ft[0]*xm + fc[0]; atg += gt[0]*xm + gcc[0]; }
            atf += ft[2]*x1 + fc[2]; atg += gt[2]*x1 + gcc[2];
            g0 = tanhf(atf)/(1.0f+expf(-atg));
        }
        {
            float atf = fb + ft[0]*x0 + fc[0] + ft[1]*x1 + fc[1] + ft[2]*x2 + fc[2];
            float atg = gb + gt[0]*x0 + gcc[0] + gt[1]*x1 + gcc[1] + gt[2]*x2 + gcc[2];
            g1 = tanhf(atf)/(1.0f+expf(-atg));
        }
        {
            float atf = fb + ft[0]*x1 + fc[0] + ft[1]*x2 + fc[1] + ft[2]*x3 + fc[2];
            float atg = gb + gt[0]*x1 + gcc[0] + gt[1]*x2 + gcc[1] + gt[2]*x3 + gcc[2];
            g2 = tanhf(atf)/(1.0f+expf(-atg));
        }
        {
            float atf = fb + ft[0]*x2 + fc[0] + ft[1]*x3 + fc[1];
            float atg = gb + gt[0]*x2 + gcc[0] + gt[1]*x3 + gcc[1];
            if (hr3){ atf += ft[2]*xq + fc[2]; atg += gt[2]*xq + gcc[2]; }
            g3 = tanhf(atf)/(1.0f+expf(-atg));
        }
        lds4[v] = make_float4(g0,g1,g2,g3);
        eg[base+v] = g0; eg[base+NN+v] = g1; eg[base+2*NN+v] = g2; eg[base+3*NN+v] = g3;
    }
    __syncthreads();
    for (int wb=0;wb<4;wb++){
        int w = wb*256 + tid;
        float4 gw = lds4[w];
        float dv = d1[w];
        float a0=gw.x*dv, a1=gw.y*dv, a2=gw.z*dv, a3=gw.w*dv;
        int cnt = ccount[w];               // padded to multiple of 8
        const int4*   ci4 = (const int4*)  (cidx + (long)w*NN);
        const float4* cw4 = (const float4*)(cw   + (long)w*NN);
        for (int e=0; e<cnt; e+=8){
            int4 ia = ci4[e>>2], ib = ci4[(e>>2)+1];
            float4 wa = cw4[e>>2], wc = cw4[(e>>2)+1];
            float4 s;
            s = lds4[ia.x]; a0 += wa.x*s.x; a1 += wa.x*s.y; a2 += wa.x*s.z; a3 += wa.x*s.w;
            s = lds4[ia.y]; a0 += wa.y*s.x; a1 += wa.y*s.y; a2 += wa.y*s.z; a3 += wa.y*s.w;
            s = lds4[ia.z]; a0 += wa.z*s.x; a1 += wa.z*s.y; a2 += wa.z*s.z; a3 += wa.z*s.w;
            s = lds4[ia.w]; a0 += wa.w*s.x; a1 += wa.w*s.y; a2 += wa.w*s.z; a3 += wa.w*s.w;
            s = lds4[ib.x]; a0 += wc.x*s.x; a1 += wc.x*s.y; a2 += wc.x*s.z; a3 += wc.x*s.w;
            s = lds4[ib.y]; a0 += wc.y*s.x; a1 += wc.y*s.y; a2 += wc.y*s.z; a3 += wc.y*s.w;
            s = lds4[ib.z]; a0 += wc.z*s.x; a1 += wc.z*s.y; a2 += wc.z*s.z; a3 += wc.z*s.w;
            s = lds4[ib.w]; a0 += wc.w*s.x; a1 += wc.w*s.y; a2 += wc.w*s.z; a3 += wc.w*s.w;
        }
        es1[base+w]=a0; es1[base+NN+w]=a1; es1[base+2*NN+w]=a2; es1[base+3*NN+w]=a3;
        float dw = d2[w];
        float b0a=gw.x*dw, b1a=gw.y*dw, b2a=gw.z*dw, b3a=gw.w*dw;
        const int4*   tc4 = (const int4*)  (topc2 + w*32);
        const float4* e24 = (const float4*)(ew2b  + w*32);
        #pragma unroll
        for (int r=0;r<8;r++){
            int4 ic = tc4[r]; float4 wv = e24[r];
            float4 s;
            s = lds4[ic.x]; b0a += wv.x*s.x; b1a += wv.x*s.y; b2a += wv.x*s.z; b3a += wv.x*s.w;
            s = lds4[ic.y]; b0a += wv.y*s.x; b1a += wv.y*s.y; b2a += wv.y*s.z; b3a += wv.y*s.w;
            s = lds4[ic.z]; b0a += wv.z*s.x; b1a += wv.z*s.y; b2a += wv.z*s.z; b3a += wv.z*s.w;
            s = lds4[ic.w]; b0a += wv.w*s.x; b1a += wv.w*s.y; b2a += wv.w*s.z; b3a += wv.w*s.w;
        }
        es2[base+w]=b0a; es2[base+NN+w]=b1a; es2[base+2*NN+w]=b2a; es2[base+3*NN+w]=b3a;
    }
}

// encoder tail: fused (mix.end) -> relu -> e32 planes (pointwise, layout-agnostic)
__global__ __launch_bounds__(256) void k_enc_tail(const float* __restrict__ Bp,
    float* __restrict__ E32, const float* __restrict__ Wt, long S)
{
    long p = (long)blockIdx.x*256 + threadIdx.x;
    float e[32];
    #pragma unroll
    for (int o2=0;o2<32;o2++) e[o2] = Wt[OEEB+o2];
    for (int i=0;i<16;i++){
        float a = Bp[(long)i*S+p], b = Bp[(long)(16+i)*S+p], c = Bp[(long)(32+i)*S+p];
        const float* w0 = Wt+OEE0+i*32;
        const float* w1 = Wt+OEE1+i*32;
        const float* w2 = Wt+OEE2+i*32;
        #pragma unroll
        for (int o2=0;o2<32;o2++) e[o2] += w0[o2]*a + w1[o2]*b + w2[o2]*c;
    }
    #pragma unroll
    for (int o2=0;o2<32;o2++){
        float v = e[o2];
        E32[(long)o2*S+p] = v>0.0f ? v : 0.0f;
    }
}

// decoder gated tconv with eout folded in: taps at pos +/- NN under [t][v] layout
// (R2 known-good form: 1 t-point per thread, 32 accumulators)
__global__ __launch_bounds__(256) void k_dec_gate(const float* __restrict__ E32,
    float* __restrict__ g, const float* __restrict__ Wt, long S)
{
    int oc = blockIdx.y;
    long pos = (long)blockIdx.x*256 + threadIdx.x;
    int t = (int)((pos>>10) & (TTL-1));
    bool hasL = (t>0), hasR = (t<TTL-1);
    float af[16], ag[16];
    #pragma unroll
    for (int o=0;o<16;o++){
        float bf = Wt[ODTF_B+oc*16+o] + Wt[OCF+oc*48+o*3+1];
        float bg = Wt[ODTG_B+oc*16+o] + Wt[OCG+oc*48+o*3+1];
        if (hasL){ bf += Wt[OCF+oc*48+o*3];   bg += Wt[OCG+oc*48+o*3]; }
        if (hasR){ bf += Wt[OCF+oc*48+o*3+2]; bg += Wt[OCG+oc*48+o*3+2]; }
        af[o]=bf; ag[o]=bg;
    }
    #pragma unroll 1
    for (int j=0;j<32;j++){
        const float* xp = E32 + (long)j*S + pos;
        float xc = xp[0];
        float xl = hasL ? xp[-NN] : 0.0f;
        float xr = hasR ? xp[NN]  : 0.0f;
        const float* wfg = Wt + ODTW2 + (long)(oc*32+j)*96;
        #pragma unroll
        for (int o=0;o<16;o++){
            af[o] += wfg[o*3]*xl + wfg[o*3+1]*xc + wfg[o*3+2]*xr;
            ag[o] += wfg[48+o*3]*xl + wfg[48+o*3+1]*xc + wfg[48+o*3+2]*xr;
        }
    }
    #pragma unroll
    for (int o=0;o<16;o++){
        g[(long)(oc*16+o)*S + pos] = tanhf(af[o])/(1.0f+expf(-ag[o]));
    }
}

// decoder fused-mix pointwise conv, SINGLE pass: one g read feeds all 96 outputs
__global__ __launch_bounds__(256) void k_dec_conv(const float* __restrict__ g,
    float* __restrict__ P12, float* __restrict__ P0p,
    const float* __restrict__ Wt, long S)
{
    long p = (long)blockIdx.x*256 + threadIdx.x;
    float a0[32], a1[32], a2[32];
    #pragma unroll
    for (int jj=0;jj<32;jj++){ a1[jj]=0.0f; a2[jj]=0.0f; a0[jj]=Wt[ODEB+jj]; }
    #pragma unroll 1
    for (int i=0;i<64;i++){
        float gv = g[(long)i*S+p];
        const float* wr = Wt + ODEALL + i*96;
        #pragma unroll
        for (int jj=0;jj<32;jj++){
            a1[jj] += wr[jj]*gv;
            a2[jj] += wr[32+jj]*gv;
            a0[jj] += wr[64+jj]*gv;
        }
    }
    #pragma unroll
    for (int jj=0;jj<32;jj++){
        P12[(long)jj*S+p]      = a1[jj];
        P12[(long)(32+jj)*S+p] = a2[jj];
        P0p[(long)jj*S+p]      = a0[jj];
    }
}

// decoder graph gather + fused tail: ch-groups of 4, each block completes Q12
// for its channels, applies relu(P0+Q12)*wc, accumulates a group-partial plane.
__global__ __launch_bounds__(256) void k_graph32f(const float* __restrict__ P1,
    const float* __restrict__ P2, const float* __restrict__ P0,
    float* __restrict__ part,
    const int* __restrict__ ccount, const int* __restrict__ cidx, const float* __restrict__ cw,
    const int* __restrict__ topc2, const float* __restrict__ ew2b,
    const float* __restrict__ d1, const float* __restrict__ d2,
    const float* __restrict__ Wt, long S)
{
    __shared__ float4 lds4[NN];   // 16 KB, re-staged per channel/dir
    int tid = threadIdx.x;
    int grp = blockIdx.y, cb = blockIdx.z, t0 = blockIdx.x*4;
    long tbase = (long)cb*NTP + (long)t0*NN;
    float res[4][4];
    #pragma unroll
    for (int wb=0;wb<4;wb++){
        #pragma unroll
        for (int k=0;k<4;k++) res[wb][k]=0.0f;
    }
    float q1[4][4];
    for (int c4=0;c4<4;c4++){
        int ch = grp*4 + c4;
        long base = (long)ch*S + tbase;
        if (c4) __syncthreads();               // protect lds4 from prev readers
        const float* s1 = P1 + base;
        for (int q=0;q<4;q++){
            int v = q*256 + tid;
            lds4[v] = make_float4(s1[v], s1[v+NN], s1[v+2*NN], s1[v+3*NN]);
        }
        __syncthreads();
        for (int wb=0;wb<4;wb++){
            int w = wb*256 + tid;
            float4 gv = lds4[w];
            float dv = d1[w];
            float a0=gv.x*dv, a1=gv.y*dv, a2=gv.z*dv, a3=gv.w*dv;
            int cnt = ccount[w];
            const int4*   ci4 = (const int4*)  (cidx + (long)w*NN);
            const float4* cw4 = (const float4*)(cw   + (long)w*NN);
            for (int e=0; e<cnt; e+=8){
                int4 ia = ci4[e>>2], ib = ci4[(e>>2)+1];
                float4 wa = cw4[e>>2], wc2 = cw4[(e>>2)+1];
                float4 s;
                s = lds4[ia.x]; a0 += wa.x*s.x; a1 += wa.x*s.y; a2 += wa.x*s.z; a3 += wa.x*s.w;
                s = lds4[ia.y]; a0 += wa.y*s.x; a1 += wa.y*s.y; a2 += wa.y*s.z; a3 += wa.y*s.w;
                s = lds4[ia.z]; a0 += wa.z*s.x; a1 += wa.z*s.y; a2 += wa.z*s.z; a3 += wa.z*s.w;
                s = lds4[ia.w]; a0 += wa.w*s.x; a1 += wa.w*s.y; a2 += wa.w*s.z; a3 += wa.w*s.w;
                s = lds4[ib.x]; a0 += wc2.x*s.x; a1 += wc2.x*s.y; a2 += wc2.x*s.z; a3 += wc2.x*s.w;
                s = lds4[ib.y]; a0 += wc2.y*s.x; a1 += wc2.y*s.y; a2 += wc2.y*s.z; a3 += wc2.y*s.w;
                s = lds4[ib.z]; a0 += wc2.z*s.x; a1 += wc2.z*s.y; a2 += wc2.z*s.z; a3 += wc2.z*s.w;
                s = lds4[ib.w]; a0 += wc2.w*s.x; a1 += wc2.w*s.y; a2 += wc2.w*s.z; a3 += wc2.w*s.w;
            }
            q1[wb][0]=a0; q1[wb][1]=a1; q1[wb][2]=a2; q1[wb][3]=a3;
        }
        __syncthreads();
        const float* s2 = P2 + base;
        for (int q=0;q<4;q++){
            int v = q*256 + tid;
            lds4[v] = make_float4(s2[v], s2[v+NN], s2[v+2*NN], s2[v+3*NN]);
        }
        __syncthreads();
        float wc = Wt[OWC+ch];
        const float* p0 = P0 + base;
        for (int wb=0;wb<4;wb++){
            int w = wb*256 + tid;
            float4 gv = lds4[w];
            float dw = d2[w];
            float c0=gv.x*dw, c1=gv.y*dw, c2=gv.z*dw, c3=gv.w*dw;
            const int4*   tc4 = (const int4*)  (topc2 + w*32);
            const float4* e24 = (const float4*)(ew2b  + w*32);
            #pragma unroll
            for (int r=0;r<8;r++){
                int4 ic = tc4[r]; float4 wv = e24[r];
                float4 s;
                s = lds4[ic.x]; c0 += wv.x*s.x; c1 += wv.x*s.y; c2 += wv.x*s.z; c3 += wv.x*s.w;
                s = lds4[ic.y]; c0 += wv.y*s.x; c1 += wv.y*s.y; c2 += wv.y*s.z; c3 += wv.y*s.w;
                s = lds4[ic.z]; c0 += wv.z*s.x; c1 += wv.z*s.y; c2 += wv.z*s.z; c3 += wv.z*s.w;
                s = lds4[ic.w]; c0 += wv.w*s.x; c1 += wv.w*s.y; c2 += wv.w*s.z; c3 += wv.w*s.w;
            }
            float e0 = p0[w]        + q1[wb][0] + c0;
            float e1 = p0[NN+w]     + q1[wb][1] + c1;
            float e2 = p0[2*NN+w]   + q1[wb][2] + c2;
            float e3 = p0[3*NN+w]   + q1[wb][3] + c3;
            e0 = e0>0.0f?e0:0.0f; e1 = e1>0.0f?e1:0.0f;
            e2 = e2>0.0f?e2:0.0f; e3 = e3>0.0f?e3:0.0f;
            res[wb][0] += wc*e0; res[wb][1] += wc*e1;
            res[wb][2] += wc*e2; res[wb][3] += wc*e3;
        }
    }
    long pb = (long)grp*S + tbase;
    for (int wb=0;wb<4;wb++){
        int w = wb*256 + tid;
        part[pb+w]      = res[wb][0];
        part[pb+NN+w]   = res[wb][1];
        part[pb+2*NN+w] = res[wb][2];
        part[pb+3*NN+w] = res[wb][3];
    }
}

// combine 8 group-partials + OBC -> out (fully contiguous store)
__global__ __launch_bounds__(256) void k_comb(const float* __restrict__ part,
    const float* __restrict__ Wt, float* __restrict__ out, long S, int b0)
{
    long p = (long)blockIdx.x*256 + threadIdx.x;
    float r = Wt[OBC];
    #pragma unroll
    for (int gp=0; gp<8; gp++) r += part[(long)gp*S+p];
    out[(long)b0*NTP + p] = r;
}

// ============ launch ============

extern "C" void kernel_launch(void* const* d_in, const int* in_sizes, int n_in,
                              void* d_out, int out_size, void* d_ws, size_t ws_size,
                              hipStream_t stream)
{
    const float* x      = (const float*)d_in[0];
    const int*   idx    = (const int*)  d_in[1];
    const float* emb1   = (const float*)d_in[2];
    const float* emb2   = (const float*)d_in[3];
    const float* lin1_w = (const float*)d_in[4];
    const float* lin1_b = (const float*)d_in[5];
    const float* lin2_w = (const float*)d_in[6];
    const float* lin2_b = (const float*)d_in[7];
    const float* w_start= (const float*)d_in[8];
    const float* b_start= (const float*)d_in[9];
    const float* etf_w  = (const float*)d_in[10];
    const float* etf_b  = (const float*)d_in[11];
    const float* etg_w  = (const float*)d_in[12];
    const float* etg_b  = (const float*)d_in[13];
    const float* eg1_w  = (const float*)d_in[14];
    const float* eg1_b  = (const float*)d_in[15];
    const float* eg2_w  = (const float*)d_in[16];
    const float* eg2_b  = (const float*)d_in[17];
    const float* eend_w = (const float*)d_in[18];
    const float* eend_b = (const float*)d_in[19];
    const float* eout_w = (const float*)d_in[20];
    const float* eout_b = (const float*)d_in[21];
    const float* dtf_w  = (const float*)d_in[22];
    const float* dtf_b  = (const float*)d_in[23];
    const float* dtg_w  = (const float*)d_in[24];
    const float* dtg_b  = (const float*)d_in[25];
    const float* dg1_w  = (const float*)d_in[26];
    const float* dg1_b  = (const float*)d_in[27];
    const float* dg2_w  = (const float*)d_in[28];
    const float* dg2_b  = (const float*)d_in[29];
    const float* dend_w = (const float*)d_in[30];
    const float* dend_b = (const float*)d_in[31];
    const float* dout_w = (const float*)d_in[32];
    const float* dout_b = (const float*)d_in[33];
    const float* w_end  = (const float*)d_in[34];
    const float* b_end  = (const float*)d_in[35];
    float* out = (float*)d_out;

    char* basep = (char*)d_ws;
    size_t cur = 0;
    auto alloc = [&](size_t bytes)->void* {
        void* p = basep + cur;
        cur = (cur + bytes + 511) & ~(size_t)511;
        return p;
    };
    float*  W     = (float*) alloc(WTOT*sizeof(float));
    double* n1    = (double*)alloc(65536*sizeof(double));
    double* n2    = (double*)alloc(65536*sizeof(double));
    double* topv  = (double*)alloc((size_t)NN*TOPK*sizeof(double));
    int*    topc  = (int*)   alloc((size_t)NN*TOPK*sizeof(int));
    double* rs1   = (double*)alloc(NN*sizeof(double));
    double* rs2   = (double*)alloc(NN*sizeof(double));
    double* colsum= (double*)alloc(NN*sizeof(double));
    float*  d1a   = (float*) alloc(NN*sizeof(float));
    float*  d2a   = (float*) alloc(NN*sizeof(float));
    int*    topc2 = (int*)   alloc((size_t)NN*32*sizeof(int));
    float*  ew2b  = (float*) alloc((size_t)NN*32*sizeof(float));
    int*    ccount= (int*)   alloc(NN*sizeof(int));
    int*    cidx  = (int*)   alloc((size_t)NN*NN*sizeof(int));
    float*  cw    = (float*) alloc((size_t)NN*NN*sizeof(float));

    // plane arena: A(64) + B(48) + C(64) channel planes of CB*NTP floats
    size_t perb = (size_t)176 * NTP * sizeof(float);
    int CB = 1;
    for (int c = 16; c >= 1; c >>= 1){
        if (cur + perb*(size_t)c <= ws_size){ CB = c; break; }
    }
    long S = (long)CB * NTP;
    float* A = (float*)alloc((size_t)64*S*sizeof(float));
    float* B = (float*)alloc((size_t)48*S*sizeof(float));
    float* C = (float*)alloc((size_t)64*S*sizeof(float));

    (void)hipMemsetAsync(colsum, 0, NN*sizeof(double), stream);
    (void)hipMemsetAsync(ccount, 0, NN*sizeof(int), stream);

    k_prep_weights<<<32,256,0,stream>>>(
        w_start,b_start, etf_w,etf_b, etg_w,etg_b, eg1_w,eg1_b, eg2_w,eg2_b,
        eend_w,eend_b, eout_w,eout_b, dtf_w,dtf_b, dtg_w,dtg_b, dg1_w,dg1_b,
        dg2_w,dg2_b, dend_w,dend_b, dout_w,dout_b, w_end,b_end, W);
    k_emb<<<256,256,0,stream>>>(idx, emb1, emb2, lin1_w, lin1_b, lin2_w, lin2_b, n1, n2);
    k_topk<<<NN,64,0,stream>>>(n1, n2, topc, topv, rs1, colsum);
    k_csc<<<4,256,0,stream>>>(topc, topv, rs1, ccount, cidx, cw);
    k_pad<<<4,256,0,stream>>>(ccount, cidx, cw);
    k_post1<<<4,256,0,stream>>>(colsum, rs1, rs2, d1a, d2a);
    k_post2<<<(NN*32+255)/256,256,0,stream>>>(topc, topv, rs2, topc2, ew2b);

    int nch = 16 / CB;
    for (int ch=0; ch<nch; ch++){
        int b0 = ch*CB;
        // encoder: fused gate+graph -> eg(B[0:16]), es1(B[16:32]), es2(B[32:48])
        k_enc_gg<<<dim3(32,16,CB),256,0,stream>>>(x, B, B+(long)16*S, B+(long)32*S, W,
            ccount,cidx,cw, topc2,ew2b, d1a,d2a, S, b0);
        // encoder tail: B[0:48] -> e32 (A[0:32])
        k_enc_tail<<<512*CB,256,0,stream>>>(B, A, W, S);
        // decoder gate (eout folded): e32(A) -> g (C[0:64])
        k_dec_gate<<<dim3(512*CB,4),256,0,stream>>>(A, C, W, S);
        // decoder fused-mix conv (single pass): g(C) -> P1,P2 (A[0:64]), P0 (B[0:32])
        k_dec_conv<<<512*CB,256,0,stream>>>(C, A, B, W, S);
        // decoder graph gather + fused tail: A(P1,P2), B(P0) -> partials (C[0:8])
        k_graph32f<<<dim3(32,8,CB),256,0,stream>>>(A, A+(long)32*S, B, C,
            ccount,cidx,cw, topc2,ew2b, d1a,d2a, W, S);
        // combine partials -> out
        k_comb<<<512*CB,256,0,stream>>>(C, W, out, S, b0);
    }
    (void)in_sizes; (void)n_in; (void)out_size;
}

// Round 5
// 3624.929 us; speedup vs baseline: 1.1061x; 1.0902x over previous
//
#include <hip/hip_runtime.h>
#include <math.h>

#define NN   1024
#define TTL  128
#define NTP  131072   // NN*TTL
#define TOPK 30

// ---- weight region offsets (in floats) ----
#define OEGTF_T 0
#define OEGTF_C 48
#define OEGTF_B 96
#define OEGTG_T 112
#define OEGTG_C 160
#define OEGTG_B 208
#define OEE0    224
#define OEE1    736
#define OEE2    1248
#define OEEB    1760
#define OEOUT_W 1792
#define OEOUT_B 3840
#define ODTF_B  16192
#define ODTG_B  28544
#define ODEB    34752
#define OWC     34784
#define OBC     34816
#define ODEALL  59456   // [i][96]: [0:32]=E1, [32:64]=E2, [64:96]=E0 (6144)
#define ODTW2   65600   // folded (tconv.eout): [oc][j=32][96] f taps 0..47, g taps 48..95 (12288)
#define OCF     77888   // f per-tap consts [oc][o][k] (192)
#define OCG     78080   // g per-tap consts (192)
#define WTOT    78272

// ============ setup kernels ============
// All folding math in fp64, stored as fp32 for the pipeline.

__global__ void k_prep_weights(
    const float* __restrict__ w_start, const float* __restrict__ b_start,
    const float* __restrict__ etf_w, const float* __restrict__ etf_b,
    const float* __restrict__ etg_w, const float* __restrict__ etg_b,
    const float* __restrict__ eg1_w, const float* __restrict__ eg1_b,
    const float* __restrict__ eg2_w, const float* __restrict__ eg2_b,
    const float* __restrict__ eend_w, const float* __restrict__ eend_b,
    const float* __restrict__ eout_w, const float* __restrict__ eout_b,
    const float* __restrict__ dtf_w, const float* __restrict__ dtf_b,
    const float* __restrict__ dtg_w, const float* __restrict__ dtg_b,
    const float* __restrict__ dg1_w, const float* __restrict__ dg1_b,
    const float* __restrict__ dg2_w, const float* __restrict__ dg2_b,
    const float* __restrict__ dend_w, const float* __restrict__ dend_b,
    const float* __restrict__ dout_w, const float* __restrict__ dout_b,
    const float* __restrict__ w_end, const float* __restrict__ b_end,
    float* __restrict__ W)
{
    int tid = blockIdx.x*blockDim.x + threadIdx.x;
    int nthr = gridDim.x*blockDim.x;
    // encoder gate collapsed through w_start: tap[o][k] = sum_i w[o,i,k]*ws[i]
    for (int id=tid; id<96; id+=nthr){
        int which = id/48; int r = id%48; int o = r/3, k = r%3;
        const float* w = which ? etg_w : etf_w;
        double t=0.0, c=0.0;
        for (int i=0;i<16;i++){
            double wv = (double)w[(o*16+i)*3+k];
            t += wv*(double)w_start[i];
            c += wv*(double)b_start[i];
        }
        W[(which?OEGTG_T:OEGTF_T)+o*3+k] = (float)t;
        W[(which?OEGTG_C:OEGTF_C)+o*3+k] = (float)c;
    }
    for (int i=tid;i<16;i+=nthr){
        W[OEGTF_B+i] = etf_b[i];
        W[OEGTG_B+i] = etg_b[i];
    }
    // encoder fused (mix . end) matrices: Ee_k[i][o2] = sum_o eend_w[o2][o]*Mk[i][o]
    for (int id=tid; id<512; id+=nthr){
        int i = id>>5, o2 = id&31;
        double s0=0.0, s1=0.0, s2=0.0;
        for (int o=0;o<16;o++){
            double m0 = (double)eg1_w[o*32+i] + (double)eg2_w[o*32+i]
                      + 0.05*((double)eg1_w[o*32+16+i] + (double)eg2_w[o*32+16+i]);
            double m1 = 0.95*(double)eg1_w[o*32+16+i];
            double m2 = 0.95*(double)eg2_w[o*32+16+i];
            double ew = (double)eend_w[o2*16+o];
            s0 += ew*m0; s1 += ew*m1; s2 += ew*m2;
        }
        W[OEE0+i*32+o2]=(float)s0; W[OEE1+i*32+o2]=(float)s1; W[OEE2+i*32+o2]=(float)s2;
    }
    for (int o2=tid; o2<32; o2+=nthr){
        double s = (double)eend_b[o2];
        for (int o=0;o<16;o++) s += (double)eend_w[o2*16+o]*((double)eg1_b[o]+(double)eg2_b[o]);
        W[OEEB+o2] = (float)s;
    }
    for (int i=tid;i<64;i+=nthr){
        W[ODTF_B+i]=dtf_b[i]; W[ODTG_B+i]=dtg_b[i];
    }
    // folded decoder tconv weights: W'[oc][j][q], q<48: f (o*3+k), q>=48: g
    for (int id=tid; id<12288; id+=nthr){
        int oc = id/3072; int rem = id%3072; int j = rem/96; int q = rem%96;
        const float* w = (q<48) ? dtf_w : dtg_w;
        int q2 = (q<48) ? q : q-48;
        int o = q2/3, k = q2%3;
        double s = 0.0;
        for (int i=0;i<64;i++)
            s += (double)w[((oc*16+o)*64+i)*3+k]*(double)eout_w[i*32+j];
        W[ODTW2+id] = (float)s;
    }
    // per-tap constants from eout_b
    for (int id=tid; id<384; id+=nthr){
        int which = id/192; int r = id%192;
        int oc = r/48; int q = r%48; int o = q/3, k = q%3;
        const float* w = which ? dtg_w : dtf_w;
        double s = 0.0;
        for (int i=0;i<64;i++)
            s += (double)w[((oc*16+o)*64+i)*3+k]*(double)eout_b[i];
        W[(which?OCG:OCF) + oc*48 + o*3 + k] = (float)s;
    }
    // decoder fused (mix . end) matrices, combined layout [i][96]
    for (int id=tid; id<6144; id+=nthr){
        int i = id/96, j = id%96;
        double s = 0.0;
        if (j < 32){
            int o2 = j;
            for (int o=0;o<64;o++){
                double m1 = 0.95*(double)dg1_w[o*128+64+i];
                s += (double)dend_w[o2*64+o]*m1;
            }
        } else if (j < 64){
            int o2 = j-32;
            for (int o=0;o<64;o++){
                double m2 = 0.95*(double)dg2_w[o*128+64+i];
                s += (double)dend_w[o2*64+o]*m2;
            }
        } else {
            int o2 = j-64;
            for (int o=0;o<64;o++){
                double m0 = (double)dg1_w[o*128+i] + (double)dg2_w[o*128+i]
                          + 0.05*((double)dg1_w[o*128+64+i] + (double)dg2_w[o*128+64+i]);
                s += (double)dend_w[o2*64+o]*m0;
            }
        }
        W[ODEALL+id] = (float)s;
    }
    for (int o2=tid; o2<32; o2+=nthr){
        double s = (double)dend_b[o2];
        for (int o=0;o<64;o++) s += (double)dend_w[o2*64+o]*((double)dg1_b[o]+(double)dg2_b[o]);
        W[ODEB+o2] = (float)s;
        double wc = 0.0;
        for (int o3=0;o3<16;o3++) wc += (double)w_end[o3]*(double)dout_w[o3*32+o2];
        W[OWC+o2] = (float)wc;
    }
    if (tid==0){
        double bc = (double)b_end[0];
        for (int o3=0;o3<16;o3++) bc += (double)w_end[o3]*(double)dout_b[o3];
        W[OBC] = (float)bc;
    }
}

// adjacency build stays fp64 so top-k SELECTION is unchanged vs baseline
__global__ void k_emb(const int* __restrict__ idxp,
                      const float* __restrict__ emb1, const float* __restrict__ emb2,
                      const float* __restrict__ l1w, const float* __restrict__ l1b,
                      const float* __restrict__ l2w, const float* __restrict__ l2b,
                      double* __restrict__ n1, double* __restrict__ n2)
{
    int id = blockIdx.x*blockDim.x + threadIdx.x;   // 65536
    int i = id>>6, d = id&63;
    int ii = idxp[i];
    double a1 = (double)l1b[d], a2 = (double)l2b[d];
    for (int k=0;k<64;k++){
        a1 += (double)emb1[ii*64+k]*(double)l1w[d*64+k];
        a2 += (double)emb2[ii*64+k]*(double)l2w[d*64+k];
    }
    n1[id] = tanh(3.0*a1);
    n2[id] = tanh(3.0*a2);
}

// single wave per row; per-lane cached local argmax
__global__ __launch_bounds__(64) void k_topk(
    const double* __restrict__ n1, const double* __restrict__ n2,
    int* __restrict__ topc, double* __restrict__ topv,
    double* __restrict__ rs1, double* __restrict__ colsum)
{
    __shared__ double arow[NN];
    __shared__ double sn1[64], sn2[64];
    int i = blockIdx.x, lane = threadIdx.x;
    sn1[lane] = n1[i*64+lane];
    sn2[lane] = n2[i*64+lane];
    __syncthreads();
    for (int jb=0;jb<16;jb++){
        int j = jb*64 + lane;
        const double* p2 = n2 + (long)j*64;
        const double* p1 = n1 + (long)j*64;
        double d1v=0.0, d2v=0.0;
        for (int d=0;d<64;d++){ d1v += sn1[d]*p2[d]; d2v += sn2[d]*p1[d]; }
        double a = tanh(3.0*(d1v - d2v));
        arow[j] = a>0.0 ? a : 0.0;
    }
    __syncthreads();
    double lv = -2.0; int lj = 1<<30;
    for (int jb=0;jb<16;jb++){
        int j = jb*64+lane;
        double v = arow[j];
        if (v>lv || (v==lv && j<lj)){ lv=v; lj=j; }
    }
    double rsum = 0.0;
    for (int r=0;r<TOPK;r++){
        double bv = lv; int bj = lj;
        for (int off=32; off>=1; off>>=1){
            double ov = __shfl_xor(bv, off, 64);
            int    oj = __shfl_xor(bj, off, 64);
            if (ov>bv || (ov==bv && oj<bj)){ bv=ov; bj=oj; }
        }
        if (lane == (bj & 63)){
            arow[bj] = -2.0;
            lv = -2.0; lj = 1<<30;
            for (int jb=0;jb<16;jb++){
                int j = jb*64+lane;
                double v = arow[j];
                if (v>lv || (v==lv && j<lj)){ lv=v; lj=j; }
            }
        }
        if (lane == 0){
            topc[i*TOPK+r] = bj;
            topv[i*TOPK+r] = bv;
            if (bv > 0.0) atomicAdd(&colsum[bj], bv);
        }
        rsum += (bv > 0.0 ? bv : 0.0);
    }
    if (lane == 0) rs1[i] = 1.0 + rsum;
}

__global__ void k_csc(const int* __restrict__ topc, const double* __restrict__ topv,
                      const double* __restrict__ rs1,
                      int* __restrict__ ccount, int* __restrict__ cidx, float* __restrict__ cw)
{
    int w = blockIdx.x*blockDim.x + threadIdx.x;
    if (w >= NN) return;
    double rv = rs1[w];
    for (int r=0;r<TOPK;r++){
        double v = topv[w*TOPK+r];
        if (v > 0.0){
            int col = topc[w*TOPK+r];
            int pos = atomicAdd(&ccount[col], 1);
            cidx[(long)col*NN+pos] = w;
            cw  [(long)col*NN+pos] = (float)(v / rv);
        }
    }
}

// pad each column's edge list to a multiple of 8 with zero-weight edges
__global__ void k_pad(int* __restrict__ ccount, int* __restrict__ cidx, float* __restrict__ cw)
{
    int col = blockIdx.x*blockDim.x + threadIdx.x;
    if (col >= NN) return;
    int cnt = ccount[col];
    int padded = (cnt + 7) & ~7;
    for (int e = cnt; e < padded; e++){
        cidx[(long)col*NN + e] = 0;
        cw  [(long)col*NN + e] = 0.0f;
    }
    ccount[col] = padded;
}

__global__ void k_post1(const double* __restrict__ colsum, const double* __restrict__ rs1,
                        double* __restrict__ rs2, float* __restrict__ d1, float* __restrict__ d2)
{
    int v = blockIdx.x*blockDim.x + threadIdx.x;
    if (v >= NN) return;
    double r2 = 1.0 + colsum[v];
    rs2[v] = r2;
    d2[v] = (float)(1.0/r2);
    d1[v] = (float)(1.0/rs1[v]);
}

// dir-1 edge lists repacked to padded [w][32] (int4/float4-aligned)
__global__ void k_post2(const int* __restrict__ topc, const double* __restrict__ topv,
                        const double* __restrict__ rs2,
                        int* __restrict__ topc2, float* __restrict__ ew2b)
{
    int e = blockIdx.x*blockDim.x + threadIdx.x;
    if (e >= NN*32) return;
    int w = e>>5, r = e&31;
    if (r < TOPK){
        double v = topv[w*TOPK+r];
        int c = topc[w*TOPK+r];
        topc2[e] = (v > 0.0) ? c : 0;
        ew2b[e]  = (v > 0.0) ? (float)(v / rs2[c]) : 0.0f;
    } else {
        topc2[e] = 0;
        ew2b[e]  = 0.0f;
    }
}

// ============ pipeline kernels (planes [ch][t][v], fp32, v contiguous) ============

// encoder: gate computed from x[B,T,N] directly; t-tile=8 (two float4 LDS arrays);
// per-w metadata amortized over 8 t-values.
__global__ __launch_bounds__(256) void k_enc_gg(const float* __restrict__ x,
    float* __restrict__ eg, float* __restrict__ es1, float* __restrict__ es2,
    const float* __restrict__ Wt,
    const int* __restrict__ ccount, const int* __restrict__ cidx, const float* __restrict__ cw,
    const int* __restrict__ topc2, const float* __restrict__ ew2b,
    const float* __restrict__ d1, const float* __restrict__ d2,
    long S, int b0)
{
    __shared__ float4 lA[NN];   // t0..t0+3
    __shared__ float4 lB[NN];   // t0+4..t0+7
    int tid = threadIdx.x, c = blockIdx.y, cb = blockIdx.z, t0 = blockIdx.x*8;
    float ft[3], fc[3], gt[3], gcc[3];
    #pragma unroll
    for (int k=0;k<3;k++){
        ft[k]=Wt[OEGTF_T+c*3+k]; fc[k]=Wt[OEGTF_C+c*3+k];
        gt[k]=Wt[OEGTG_T+c*3+k]; gcc[k]=Wt[OEGTG_C+c*3+k];
    }
    float fb = Wt[OEGTF_B+c], gb = Wt[OEGTG_B+c];
    const float* xb = x + (long)(b0+cb)*NTP + (long)t0*NN;
    long base = (long)c*S + (long)cb*NTP + (long)t0*NN;
    bool hl0 = (t0>0), hr7 = (t0+8<TTL);
    for (int q=0;q<4;q++){
        int v = q*256 + tid;
        float xr[10];
        xr[0] = hl0 ? xb[v-NN] : 0.0f;
        #pragma unroll
        for (int k=0;k<8;k++) xr[k+1] = xb[v+(long)k*NN];
        xr[9] = hr7 ? xb[v+(long)8*NN] : 0.0f;
        float gg[8];
        #pragma unroll
        for (int k=0;k<8;k++){
            float atf = fb + ft[1]*xr[k+1] + fc[1];
            float atg = gb + gt[1]*xr[k+1] + gcc[1];
            bool hL = (k>0) || hl0;
            bool hR = (k<7) || hr7;
            if (hL){ atf += ft[0]*xr[k] + fc[0]; atg += gt[0]*xr[k] + gcc[0]; }
            if (hR){ atf += ft[2]*xr[k+2] + fc[2]; atg += gt[2]*xr[k+2] + gcc[2]; }
            gg[k] = tanhf(atf)/(1.0f+expf(-atg));
            eg[base + (long)k*NN + v] = gg[k];
        }
        lA[v] = make_float4(gg[0],gg[1],gg[2],gg[3]);
        lB[v] = make_float4(gg[4],gg[5],gg[6],gg[7]);
    }
    __syncthreads();
    for (int wb=0;wb<4;wb++){
        int w = wb*256 + tid;
        float4 ga = lA[w], gbv = lB[w];
        float dv = d1[w];
        float a0=ga.x*dv, a1=ga.y*dv, a2=ga.z*dv, a3=ga.w*dv;
        float a4=gbv.x*dv, a5=gbv.y*dv, a6=gbv.z*dv, a7=gbv.w*dv;
        int cnt = ccount[w];               // padded to multiple of 8
        const int4*   ci4 = (const int4*)  (cidx + (long)w*NN);
        const float4* cw4 = (const float4*)(cw   + (long)w*NN);
        for (int e=0; e<cnt; e+=4){
            int4 ia = ci4[e>>2];
            float4 wa = cw4[e>>2];
            float4 s, u;
            s = lA[ia.x]; u = lB[ia.x];
            a0 += wa.x*s.x; a1 += wa.x*s.y; a2 += wa.x*s.z; a3 += wa.x*s.w;
            a4 += wa.x*u.x; a5 += wa.x*u.y; a6 += wa.x*u.z; a7 += wa.x*u.w;
            s = lA[ia.y]; u = lB[ia.y];
            a0 += wa.y*s.x; a1 += wa.y*s.y; a2 += wa.y*s.z; a3 += wa.y*s.w;
            a4 += wa.y*u.x; a5 += wa.y*u.y; a6 += wa.y*u.z; a7 += wa.y*u.w;
            s = lA[ia.z]; u = lB[ia.z];
            a0 += wa.z*s.x; a1 += wa.z*s.y; a2 += wa.z*s.z; a3 += wa.z*s.w;
            a4 += wa.z*u.x; a5 += wa.z*u.y; a6 += wa.z*u.z; a7 += wa.z*u.w;
            s = lA[ia.w]; u = lB[ia.w];
            a0 += wa.w*s.x; a1 += wa.w*s.y; a2 += wa.w*s.z; a3 += wa.w*s.w;
            a4 += wa.w*u.x; a5 += wa.w*u.y; a6 += wa.w*u.z; a7 += wa.w*u.w;
        }
        es1[base+w]=a0; es1[base+NN+w]=a1; es1[base+2*NN+w]=a2; es1[base+3*NN+w]=a3;
        es1[base+4*NN+w]=a4; es1[base+5*NN+w]=a5; es1[base+6*NN+w]=a6; es1[base+7*NN+w]=a7;
        float dw = d2[w];
        a0=ga.x*dw; a1=ga.y*dw; a2=ga.z*dw; a3=ga.w*dw;
        a4=gbv.x*dw; a5=gbv.y*dw; a6=gbv.z*dw; a7=gbv.w*dw;
        const int4*   tc4 = (const int4*)  (topc2 + w*32);
        const float4* e24 = (const float4*)(ew2b  + w*32);
        #pragma unroll
        for (int r=0;r<8;r++){
            int4 ic = tc4[r]; float4 wv = e24[r];
            float4 s, u;
            s = lA[ic.x]; u = lB[ic.x];
            a0 += wv.x*s.x; a1 += wv.x*s.y; a2 += wv.x*s.z; a3 += wv.x*s.w;
            a4 += wv.x*u.x; a5 += wv.x*u.y; a6 += wv.x*u.z; a7 += wv.x*u.w;
            s = lA[ic.y]; u = lB[ic.y];
            a0 += wv.y*s.x; a1 += wv.y*s.y; a2 += wv.y*s.z; a3 += wv.y*s.w;
            a4 += wv.y*u.x; a5 += wv.y*u.y; a6 += wv.y*u.z; a7 += wv.y*u.w;
            s = lA[ic.z]; u = lB[ic.z];
            a0 += wv.z*s.x; a1 += wv.z*s.y; a2 += wv.z*s.z; a3 += wv.z*s.w;
            a4 += wv.z*u.x; a5 += wv.z*u.y; a6 += wv.z*u.z; a7 += wv.z*u.w;
            s = lA[ic.w]; u = lB[ic.w];
            a0 += wv.w*s.x; a1 += wv.w*s.y; a2 += wv.w*s.z; a3 += wv.w*s.w;
            a4 += wv.w*u.x; a5 += wv.w*u.y; a6 += wv.w*u.z; a7 += wv.w*u.w;
        }
        es2[base+w]=a0; es2[base+NN+w]=a1; es2[base+2*NN+w]=a2; es2[base+3*NN+w]=a3;
        es2[base+4*NN+w]=a4; es2[base+5*NN+w]=a5; es2[base+6*NN+w]=a6; es2[base+7*NN+w]=a7;
    }
}

// encoder tail: fused (mix.end) -> relu -> e32 planes (pointwise, layout-agnostic)
__global__ __launch_bounds__(256) void k_enc_tail(const float* __restrict__ Bp,
    float* __restrict__ E32, const float* __restrict__ Wt, long S)
{
    long p = (long)blockIdx.x*256 + threadIdx.x;
    float e[32];
    #pragma unroll
    for (int o2=0;o2<32;o2++) e[o2] = Wt[OEEB+o2];
    for (int i=0;i<16;i++){
        float a = Bp[(long)i*S+p], b = Bp[(long)(16+i)*S+p], c = Bp[(long)(32+i)*S+p];
        const float* w0 = Wt+OEE0+i*32;
        const float* w1 = Wt+OEE1+i*32;
        const float* w2 = Wt+OEE2+i*32;
        #pragma unroll
        for (int o2=0;o2<32;o2++) e[o2] += w0[o2]*a + w1[o2]*b + w2[o2]*c;
    }
    #pragma unroll
    for (int o2=0;o2<32;o2++){
        float v = e[o2];
        E32[(long)o2*S+p] = v>0.0f ? v : 0.0f;
    }
}

// decoder gated tconv with eout folded in (R2 known-good: 1 t-point/thread)
__global__ __launch_bounds__(256) void k_dec_gate(const float* __restrict__ E32,
    float* __restrict__ g, const float* __restrict__ Wt, long S)
{
    int oc = blockIdx.y;
    long pos = (long)blockIdx.x*256 + threadIdx.x;
    int t = (int)((pos>>10) & (TTL-1));
    bool hasL = (t>0), hasR = (t<TTL-1);
    float af[16], ag[16];
    #pragma unroll
    for (int o=0;o<16;o++){
        float bf = Wt[ODTF_B+oc*16+o] + Wt[OCF+oc*48+o*3+1];
        float bg = Wt[ODTG_B+oc*16+o] + Wt[OCG+oc*48+o*3+1];
        if (hasL){ bf += Wt[OCF+oc*48+o*3];   bg += Wt[OCG+oc*48+o*3]; }
        if (hasR){ bf += Wt[OCF+oc*48+o*3+2]; bg += Wt[OCG+oc*48+o*3+2]; }
        af[o]=bf; ag[o]=bg;
    }
    #pragma unroll 1
    for (int j=0;j<32;j++){
        const float* xp = E32 + (long)j*S + pos;
        float xc = xp[0];
        float xl = hasL ? xp[-NN] : 0.0f;
        float xr = hasR ? xp[NN]  : 0.0f;
        const float* wfg = Wt + ODTW2 + (long)(oc*32+j)*96;
        #pragma unroll
        for (int o=0;o<16;o++){
            af[o] += wfg[o*3]*xl + wfg[o*3+1]*xc + wfg[o*3+2]*xr;
            ag[o] += wfg[48+o*3]*xl + wfg[48+o*3+1]*xc + wfg[48+o*3+2]*xr;
        }
    }
    #pragma unroll
    for (int o=0;o<16;o++){
        g[(long)(oc*16+o)*S + pos] = tanhf(af[o])/(1.0f+expf(-ag[o]));
    }
}

// decoder fused-mix pointwise conv, 2-pass (R2 known-good form)
__global__ __launch_bounds__(256) void k_dec_conv(const float* __restrict__ g,
    float* __restrict__ Cp, float* __restrict__ P0p,
    const float* __restrict__ Wt, long S)
{
    long p = (long)blockIdx.x*256 + threadIdx.x;
    int jc = blockIdx.y;
    if (jc == 0){
        float a1[32], a2[32];
        #pragma unroll
        for (int jj=0;jj<32;jj++){ a1[jj]=0.0f; a2[jj]=0.0f; }
        #pragma unroll 1
        for (int i=0;i<64;i++){
            float gv = g[(long)i*S+p];
            const float* wr = Wt + ODEALL + i*96;
            #pragma unroll
            for (int jj=0;jj<32;jj++){ a1[jj] += wr[jj]*gv; a2[jj] += wr[32+jj]*gv; }
        }
        #pragma unroll
        for (int jj=0;jj<32;jj++){
            Cp[(long)jj*S+p] = a1[jj];
            Cp[(long)(32+jj)*S+p] = a2[jj];
        }
    } else {
        float a0[32];
        #pragma unroll
        for (int jj=0;jj<32;jj++) a0[jj] = Wt[ODEB+jj];
        #pragma unroll 1
        for (int i=0;i<64;i++){
            float gv = g[(long)i*S+p];
            const float* wr = Wt + ODEALL + i*96 + 64;
            #pragma unroll
            for (int jj=0;jj<32;jj++) a0[jj] += wr[jj]*gv;
        }
        #pragma unroll
        for (int jj=0;jj<32;jj++) P0p[(long)jj*S+p] = a0[jj];
    }
}

// decoder graph gather + fused tail, t-tile=8: ch-groups of 4, per-channel Q12,
// relu(P0+Q12)*wc accumulated into one group-partial plane.
__global__ __launch_bounds__(256) void k_graph32f(const float* __restrict__ P1,
    const float* __restrict__ P2, const float* __restrict__ P0,
    float* __restrict__ part,
    const int* __restrict__ ccount, const int* __restrict__ cidx, const float* __restrict__ cw,
    const int* __restrict__ topc2, const float* __restrict__ ew2b,
    const float* __restrict__ d1, const float* __restrict__ d2,
    const float* __restrict__ Wt, long S)
{
    __shared__ float4 lA[NN];   // t0..t0+3
    __shared__ float4 lB[NN];   // t0+4..t0+7
    int tid = threadIdx.x;
    int grp = blockIdx.y, cb = blockIdx.z, t0 = blockIdx.x*8;
    long tbase = (long)cb*NTP + (long)t0*NN;
    float res[4][8];
    #pragma unroll
    for (int wb=0;wb<4;wb++){
        #pragma unroll
        for (int k=0;k<8;k++) res[wb][k]=0.0f;
    }
    float q1[4][8];
    for (int c4=0;c4<4;c4++){
        int ch = grp*4 + c4;
        long base = (long)ch*S + tbase;
        if (c4) __syncthreads();
        const float* s1 = P1 + base;
        for (int q=0;q<4;q++){
            int v = q*256 + tid;
            lA[v] = make_float4(s1[v], s1[v+NN], s1[v+2*NN], s1[v+3*NN]);
            lB[v] = make_float4(s1[v+4*NN], s1[v+5*NN], s1[v+6*NN], s1[v+7*NN]);
        }
        __syncthreads();
        for (int wb=0;wb<4;wb++){
            int w = wb*256 + tid;
            float4 ga = lA[w], gbv = lB[w];
            float dv = d1[w];
            float a0=ga.x*dv, a1=ga.y*dv, a2=ga.z*dv, a3=ga.w*dv;
            float a4=gbv.x*dv, a5=gbv.y*dv, a6=gbv.z*dv, a7=gbv.w*dv;
            int cnt = ccount[w];
            const int4*   ci4 = (const int4*)  (cidx + (long)w*NN);
            const float4* cw4 = (const float4*)(cw   + (long)w*NN);
            for (int e=0; e<cnt; e+=4){
                int4 ia = ci4[e>>2];
                float4 wa = cw4[e>>2];
                float4 s, u;
                s = lA[ia.x]; u = lB[ia.x];
                a0 += wa.x*s.x; a1 += wa.x*s.y; a2 += wa.x*s.z; a3 += wa.x*s.w;
                a4 += wa.x*u.x; a5 += wa.x*u.y; a6 += wa.x*u.z; a7 += wa.x*u.w;
                s = lA[ia.y]; u = lB[ia.y];
                a0 += wa.y*s.x; a1 += wa.y*s.y; a2 += wa.y*s.z; a3 += wa.y*s.w;
                a4 += wa.y*u.x; a5 += wa.y*u.y; a6 += wa.y*u.z; a7 += wa.y*u.w;
                s = lA[ia.z]; u = lB[ia.z];
                a0 += wa.z*s.x; a1 += wa.z*s.y; a2 += wa.z*s.z; a3 += wa.z*s.w;
                a4 += wa.z*u.x; a5 += wa.z*u.y; a6 += wa.z*u.z; a7 += wa.z*u.w;
                s = lA[ia.w]; u = lB[ia.w];
                a0 += wa.w*s.x; a1 += wa.w*s.y; a2 += wa.w*s.z; a3 += wa.w*s.w;
                a4 += wa.w*u.x; a5 += wa.w*u.y; a6 += wa.w*u.z; a7 += wa.w*u.w;
            }
            q1[wb][0]=a0; q1[wb][1]=a1; q1[wb][2]=a2; q1[wb][3]=a3;
            q1[wb][4]=a4; q1[wb][5]=a5; q1[wb][6]=a6; q1[wb][7]=a7;
        }
        __syncthreads();
        const float* s2 = P2 + base;
        for (int q=0;q<4;q++){
            int v = q*256 + tid;
            lA[v] = make_float4(s2[v], s2[v+NN], s2[v+2*NN], s2[v+3*NN]);
            lB[v] = make_float4(s2[v+4*NN], s2[v+5*NN], s2[v+6*NN], s2[v+7*NN]);
        }
        __syncthreads();
        float wc = Wt[OWC+ch];
        const float* p0 = P0 + base;
        for (int wb=0;wb<4;wb++){
            int w = wb*256 + tid;
            float4 ga = lA[w], gbv = lB[w];
            float dw = d2[w];
            float a0=ga.x*dw, a1=ga.y*dw, a2=ga.z*dw, a3=ga.w*dw;
            float a4=gbv.x*dw, a5=gbv.y*dw, a6=gbv.z*dw, a7=gbv.w*dw;
            const int4*   tc4 = (const int4*)  (topc2 + w*32);
            const float4* e24 = (const float4*)(ew2b  + w*32);
            #pragma unroll
            for (int r=0;r<8;r++){
                int4 ic = tc4[r]; float4 wv = e24[r];
                float4 s, u;
                s = lA[ic.x]; u = lB[ic.x];
                a0 += wv.x*s.x; a1 += wv.x*s.y; a2 += wv.x*s.z; a3 += wv.x*s.w;
                a4 += wv.x*u.x; a5 += wv.x*u.y; a6 += wv.x*u.z; a7 += wv.x*u.w;
                s = lA[ic.y]; u = lB[ic.y];
                a0 += wv.y*s.x; a1 += wv.y*s.y; a2 += wv.y*s.z; a3 += wv.y*s.w;
                a4 += wv.y*u.x; a5 += wv.y*u.y; a6 += wv.y*u.z; a7 += wv.y*u.w;
                s = lA[ic.z]; u = lB[ic.z];
                a0 += wv.z*s.x; a1 += wv.z*s.y; a2 += wv.z*s.z; a3 += wv.z*s.w;
                a4 += wv.z*u.x; a5 += wv.z*u.y; a6 += wv.z*u.z; a7 += wv.z*u.w;
                s = lA[ic.w]; u = lB[ic.w];
                a0 += wv.w*s.x; a1 += wv.w*s.y; a2 += wv.w*s.z; a3 += wv.w*s.w;
                a4 += wv.w*u.x; a5 += wv.w*u.y; a6 += wv.w*u.z; a7 += wv.w*u.w;
            }
            float e0,e1,e2,e3,e4,e5,e6,e7;
            e0 = p0[w]      + q1[wb][0] + a0;
            e1 = p0[NN+w]   + q1[wb][1] + a1;
            e2 = p0[2*NN+w] + q1[wb][2] + a2;
            e3 = p0[3*NN+w] + q1[wb][3] + a3;
            e4 = p0[4*NN+w] + q1[wb][4] + a4;
            e5 = p0[5*NN+w] + q1[wb][5] + a5;
            e6 = p0[6*NN+w] + q1[wb][6] + a6;
            e7 = p0[7*NN+w] + q1[wb][7] + a7;
            e0 = e0>0.0f?e0:0.0f; e1 = e1>0.0f?e1:0.0f;
            e2 = e2>0.0f?e2:0.0f; e3 = e3>0.0f?e3:0.0f;
            e4 = e4>0.0f?e4:0.0f; e5 = e5>0.0f?e5:0.0f;
            e6 = e6>0.0f?e6:0.0f; e7 = e7>0.0f?e7:0.0f;
            res[wb][0] += wc*e0; res[wb][1] += wc*e1;
            res[wb][2] += wc*e2; res[wb][3] += wc*e3;
            res[wb][4] += wc*e4; res[wb][5] += wc*e5;
            res[wb][6] += wc*e6; res[wb][7] += wc*e7;
        }
    }
    long pb = (long)grp*S + tbase;
    for (int wb=0;wb<4;wb++){
        int w = wb*256 + tid;
        #pragma unroll
        for (int k=0;k<8;k++) part[pb+(long)k*NN+w] = res[wb][k];
    }
}

// combine 8 group-partials + OBC -> out (fully contiguous store)
__global__ __launch_bounds__(256) void k_comb(const float* __restrict__ part,
    const float* __restrict__ Wt, float* __restrict__ out, long S, int b0)
{
    long p = (long)blockIdx.x*256 + threadIdx.x;
    float r = Wt[OBC];
    #pragma unroll
    for (int gp=0; gp<8; gp++) r += part[(long)gp*S+p];
    out[(long)b0*NTP + p] = r;
}

// ============ launch ============

extern "C" void kernel_launch(void* const* d_in, const int* in_sizes, int n_in,
                              void* d_out, int out_size, void* d_ws, size_t ws_size,
                              hipStream_t stream)
{
    const float* x      = (const float*)d_in[0];
    const int*   idx    = (const int*)  d_in[1];
    const float* emb1   = (const float*)d_in[2];
    const float* emb2   = (const float*)d_in[3];
    const float* lin1_w = (const float*)d_in[4];
    const float* lin1_b = (const float*)d_in[5];
    const float* lin2_w = (const float*)d_in[6];
    const float* lin2_b = (const float*)d_in[7];
    const float* w_start= (const float*)d_in[8];
    const float* b_start= (const float*)d_in[9];
    const float* etf_w  = (const float*)d_in[10];
    const float* etf_b  = (const float*)d_in[11];
    const float* etg_w  = (const float*)d_in[12];
    const float* etg_b  = (const float*)d_in[13];
    const float* eg1_w  = (const float*)d_in[14];
    const float* eg1_b  = (const float*)d_in[15];
    const float* eg2_w  = (const float*)d_in[16];
    const float* eg2_b  = (const float*)d_in[17];
    const float* eend_w = (const float*)d_in[18];
    const float* eend_b = (const float*)d_in[19];
    const float* eout_w = (const float*)d_in[20];
    const float* eout_b = (const float*)d_in[21];
    const float* dtf_w  = (const float*)d_in[22];
    const float* dtf_b  = (const float*)d_in[23];
    const float* dtg_w  = (const float*)d_in[24];
    const float* dtg_b  = (const float*)d_in[25];
    const float* dg1_w  = (const float*)d_in[26];
    const float* dg1_b  = (const float*)d_in[27];
    const float* dg2_w  = (const float*)d_in[28];
    const float* dg2_b  = (const float*)d_in[29];
    const float* dend_w = (const float*)d_in[30];
    const float* dend_b = (const float*)d_in[31];
    const float* dout_w = (const float*)d_in[32];
    const float* dout_b = (const float*)d_in[33];
    const float* w_end  = (const float*)d_in[34];
    const float* b_end  = (const float*)d_in[35];
    float* out = (float*)d_out;

    char* basep = (char*)d_ws;
    size_t cur = 0;
    auto alloc = [&](size_t bytes)->void* {
        void* p = basep + cur;
        cur = (cur + bytes + 511) & ~(size_t)511;
        return p;
    };
    float*  W     = (float*) alloc(WTOT*sizeof(float));
    double* n1    = (double*)alloc(65536*sizeof(double));
    double* n2    = (double*)alloc(65536*sizeof(double));
    double* topv  = (double*)alloc((size_t)NN*TOPK*sizeof(double));
    int*    topc  = (int*)   alloc((size_t)NN*TOPK*sizeof(int));
    double* rs1   = (double*)alloc(NN*sizeof(double));
    double* rs2   = (double*)alloc(NN*sizeof(double));
    double* colsum= (double*)alloc(NN*sizeof(double));
    float*  d1a   = (float*) alloc(NN*sizeof(float));
    float*  d2a   = (float*) alloc(NN*sizeof(float));
    int*    topc2 = (int*)   alloc((size_t)NN*32*sizeof(int));
    float*  ew2b  = (float*) alloc((size_t)NN*32*sizeof(float));
    int*    ccount= (int*)   alloc(NN*sizeof(int));
    int*    cidx  = (int*)   alloc((size_t)NN*NN*sizeof(int));
    float*  cw    = (float*) alloc((size_t)NN*NN*sizeof(float));

    // plane arena: A(64) + B(48) + C(64) channel planes of CB*NTP floats
    size_t perb = (size_t)176 * NTP * sizeof(float);
    int CB = 1;
    for (int c = 16; c >= 1; c >>= 1){
        if (cur + perb*(size_t)c <= ws_size){ CB = c; break; }
    }
    long S = (long)CB * NTP;
    float* A = (float*)alloc((size_t)64*S*sizeof(float));
    float* B = (float*)alloc((size_t)48*S*sizeof(float));
    float* C = (float*)alloc((size_t)64*S*sizeof(float));

    (void)hipMemsetAsync(colsum, 0, NN*sizeof(double), stream);
    (void)hipMemsetAsync(ccount, 0, NN*sizeof(int), stream);

    k_prep_weights<<<32,256,0,stream>>>(
        w_start,b_start, etf_w,etf_b, etg_w,etg_b, eg1_w,eg1_b, eg2_w,eg2_b,
        eend_w,eend_b, eout_w,eout_b, dtf_w,dtf_b, dtg_w,dtg_b, dg1_w,dg1_b,
        dg2_w,dg2_b, dend_w,dend_b, dout_w,dout_b, w_end,b_end, W);
    k_emb<<<256,256,0,stream>>>(idx, emb1, emb2, lin1_w, lin1_b, lin2_w, lin2_b, n1, n2);
    k_topk<<<NN,64,0,stream>>>(n1, n2, topc, topv, rs1, colsum);
    k_csc<<<4,256,0,stream>>>(topc, topv, rs1, ccount, cidx, cw);
    k_pad<<<4,256,0,stream>>>(ccount, cidx, cw);
    k_post1<<<4,256,0,stream>>>(colsum, rs1, rs2, d1a, d2a);
    k_post2<<<(NN*32+255)/256,256,0,stream>>>(topc, topv, rs2, topc2, ew2b);

    int nch = 16 / CB;
    for (int ch=0; ch<nch; ch++){
        int b0 = ch*CB;
        // encoder: fused gate+graph (t-tile 8) -> eg(B[0:16]), es1(B[16:32]), es2(B[32:48])
        k_enc_gg<<<dim3(16,16,CB),256,0,stream>>>(x, B, B+(long)16*S, B+(long)32*S, W,
            ccount,cidx,cw, topc2,ew2b, d1a,d2a, S, b0);
        // encoder tail: B[0:48] -> e32 (A[0:32])
        k_enc_tail<<<512*CB,256,0,stream>>>(B, A, W, S);
        // decoder gate (eout folded): e32(A) -> g (C[0:64])
        k_dec_gate<<<dim3(512*CB,4),256,0,stream>>>(A, C, W, S);
        // decoder fused-mix conv (2-pass): g(C) -> P1,P2 (A[0:64]), P0 (B[0:32])
        k_dec_conv<<<dim3(512*CB,2),256,0,stream>>>(C, A, B, W, S);
        // decoder graph gather + fused tail (t-tile 8): A(P1,P2), B(P0) -> partials (C[0:8])
        k_graph32f<<<dim3(16,8,CB),256,0,stream>>>(A, A+(long)32*S, B, C,
            ccount,cidx,cw, topc2,ew2b, d1a,d2a, W, S);
        // combine partials -> out
        k_comb<<<512*CB,256,0,stream>>>(C, W, out, S, b0);
    }
    (void)in_sizes; (void)n_in; (void)out_size;
}